// Round 1
// baseline (1518.370 us; speedup 1.0000x reference)
//
#include <hip/hip_runtime.h>

// ---------------------------------------------------------------------------
// GraphSAGE 3-layer encoder, fp32.
// N=50000 nodes, E=640000 edges, channels 32 -> 64 -> 128 -> 64.
// Layer l: out = mean_{j in N(i)} x_j @ w_l + b + x_i @ w_r   (+relu for l=1,2)
// Layers 1,2: aggregate-then-transform (d_in < d_out).
// Layer 3: transform-then-aggregate (mean is linear; aggregate 64ch not 128ch).
// ---------------------------------------------------------------------------

__global__ void count_kernel(const int* __restrict__ dst, float* __restrict__ cnt, int nE) {
    int e = blockIdx.x * blockDim.x + threadIdx.x;
    if (e < nE) unsafeAtomicAdd(&cnt[dst[e]], 1.0f);
}

__global__ void invert_kernel(float* __restrict__ cnt, int n) {
    int i = blockIdx.x * blockDim.x + threadIdx.x;
    if (i < n) cnt[i] = 1.0f / fmaxf(cnt[i], 1.0f);
}

// scatter-add x[src[e]] (D floats) into agg[dst[e]]; 1 thread = 1 edge x float4
template<int D>
__global__ void scatter_kernel(const float* __restrict__ x, const int* __restrict__ src,
                               const int* __restrict__ dst, float* __restrict__ agg, int nE) {
    constexpr int VPE = D / 4;                    // float4 chunks per edge
    int tid = blockIdx.x * blockDim.x + threadIdx.x;
    int e = tid / VPE;
    int c = tid % VPE;
    if (e >= nE) return;
    int s = src[e];
    int d = dst[e];
    float4 v = reinterpret_cast<const float4*>(x)[(size_t)s * VPE + c];
    float* p = agg + (size_t)d * D + (size_t)c * 4;
    unsafeAtomicAdd(p + 0, v.x);
    unsafeAtomicAdd(p + 1, v.y);
    unsafeAtomicAdd(p + 2, v.z);
    unsafeAtomicAdd(p + 3, v.w);
}

// out[i, oc0:oc0+OCB] = act( [SCALE0? inv[i]*r0[i] : r0[i] | r1[i]] @ [w0 ; w1]
//                            + bias + ADDAGG? inv[i]*aggadd[i] )
// Block: 256 threads; OCG = OCB/4 oc-groups, NG = 256/OCG node-groups, CN nodes/thread.
template<int D0, int D1, int DOUT, int OCB, int CN,
         bool SCALE0, bool ADDAGG, bool BIAS, bool RELU>
__global__ __launch_bounds__(256) void xform_kernel(
    const float* __restrict__ r0, const float* __restrict__ r1,
    const float* __restrict__ w0, const float* __restrict__ w1,
    const float* __restrict__ bias, const float* __restrict__ inv,
    const float* __restrict__ aggadd, float* __restrict__ out, int nNodes)
{
    constexpr int K = D0 + D1;
    constexpr int OCG = OCB / 4;
    constexpr int NG = 256 / OCG;
    constexpr int NT = NG * CN;
    constexpr int RSTRIDE = K + 4;                // pad keeps 16B align + breaks bank aliasing

    __shared__ float wl[K * OCB];
    __shared__ float rows[NT * RSTRIDE];

    const int tid = threadIdx.x;
    const int node0 = blockIdx.x * NT;
    const int oc0 = blockIdx.y * OCB;

    // ---- stage weight columns [oc0, oc0+OCB) of w0 (D0 rows) then w1 (D1 rows)
    {
        float4* wl4 = reinterpret_cast<float4*>(wl);
        const float4* w04 = reinterpret_cast<const float4*>(w0);
        constexpr int C = OCB / 4;
        for (int idx = tid; idx < D0 * C; idx += 256) {
            int k = idx / C, c = idx % C;
            wl4[idx] = w04[(size_t)k * (DOUT / 4) + oc0 / 4 + c];
        }
        if constexpr (D1 > 0) {
            const float4* w14 = reinterpret_cast<const float4*>(w1);
            for (int idx = tid; idx < D1 * C; idx += 256) {
                int k = idx / C, c = idx % C;
                wl4[D0 * C + idx] = w14[(size_t)k * (DOUT / 4) + oc0 / 4 + c];
            }
        }
    }
    // ---- stage node rows: [scaled r0 | r1]
    {
        constexpr int C4 = K / 4;
        const float4* r04 = reinterpret_cast<const float4*>(r0);
        for (int idx = tid; idx < NT * C4; idx += 256) {
            int n = idx / C4, c4 = idx % C4;
            int node = node0 + n;
            float4 v = make_float4(0.f, 0.f, 0.f, 0.f);
            if (node < nNodes) {
                if (D1 == 0 || c4 < D0 / 4) {
                    v = r04[(size_t)node * (D0 / 4) + c4];
                    if constexpr (SCALE0) {
                        float s = inv[node];
                        v.x *= s; v.y *= s; v.z *= s; v.w *= s;
                    }
                } else {
                    if constexpr (D1 > 0) {
                        const float4* r14 = reinterpret_cast<const float4*>(r1);
                        v = r14[(size_t)node * (D1 / 4) + (c4 - D0 / 4)];
                    }
                }
            }
            *reinterpret_cast<float4*>(&rows[n * RSTRIDE + c4 * 4]) = v;
        }
    }
    __syncthreads();

    const int ocg = tid % OCG;
    const int ng = tid / OCG;

    float acc[CN][4];
#pragma unroll
    for (int i = 0; i < CN; ++i) { acc[i][0] = acc[i][1] = acc[i][2] = acc[i][3] = 0.f; }

    const float4* wl4 = reinterpret_cast<const float4*>(wl);
#pragma unroll 4
    for (int k = 0; k < K; ++k) {
        float4 wv = wl4[k * OCG + ocg];
#pragma unroll
        for (int i = 0; i < CN; ++i) {
            float rv = rows[(ng * CN + i) * RSTRIDE + k];
            acc[i][0] = fmaf(rv, wv.x, acc[i][0]);
            acc[i][1] = fmaf(rv, wv.y, acc[i][1]);
            acc[i][2] = fmaf(rv, wv.z, acc[i][2]);
            acc[i][3] = fmaf(rv, wv.w, acc[i][3]);
        }
    }

    const int oc = oc0 + ocg * 4;
#pragma unroll
    for (int i = 0; i < CN; ++i) {
        int node = node0 + ng * CN + i;
        if (node >= nNodes) continue;
        float4 o = make_float4(acc[i][0], acc[i][1], acc[i][2], acc[i][3]);
        if constexpr (BIAS) {
            o.x += bias[oc + 0]; o.y += bias[oc + 1];
            o.z += bias[oc + 2]; o.w += bias[oc + 3];
        }
        if constexpr (ADDAGG) {
            float s = inv[node];
            float4 a = reinterpret_cast<const float4*>(aggadd)[(size_t)node * (DOUT / 4) + oc / 4];
            o.x = fmaf(s, a.x, o.x); o.y = fmaf(s, a.y, o.y);
            o.z = fmaf(s, a.z, o.z); o.w = fmaf(s, a.w, o.w);
        }
        if constexpr (RELU) {
            o.x = fmaxf(o.x, 0.f); o.y = fmaxf(o.y, 0.f);
            o.z = fmaxf(o.z, 0.f); o.w = fmaxf(o.w, 0.f);
        }
        reinterpret_cast<float4*>(out)[(size_t)node * (DOUT / 4) + oc / 4] = o;
    }
}

extern "C" void kernel_launch(void* const* d_in, const int* in_sizes, int n_in,
                              void* d_out, int out_size, void* d_ws, size_t ws_size,
                              hipStream_t stream) {
    const float* x   = (const float*)d_in[0];
    const int*   ei  = (const int*)d_in[1];
    const float* w1l = (const float*)d_in[2];
    const float* b1  = (const float*)d_in[3];
    const float* w1r = (const float*)d_in[4];
    const float* w2l = (const float*)d_in[5];
    const float* b2  = (const float*)d_in[6];
    const float* w2r = (const float*)d_in[7];
    const float* w3l = (const float*)d_in[8];
    const float* b3  = (const float*)d_in[9];
    const float* w3r = (const float*)d_in[10];

    const int nN = in_sizes[0] / 32;   // 50000
    const int nE = in_sizes[1] / 2;    // 640000
    const int* src = ei;
    const int* dst = ei + nE;

    float* ws = (float*)d_ws;
    size_t o = 0;
    auto alloc = [&](size_t nfloats) {
        float* p = ws + o;
        o += (nfloats + 63) & ~(size_t)63;
        return p;
    };
    float* inv = alloc(nN);                  // counts -> inverse counts
    float* agg = alloc((size_t)nN * 64);     // aggregation buffer (max 64 ch)
    float* h1  = alloc((size_t)nN * 64);     // layer-1 output; reused as t3
    float* h2  = alloc((size_t)nN * 128);    // layer-2 output
    float* t3  = h1;                         // h1 is dead once h2 is computed

    // ---- degree counts (shared by all layers)
    hipMemsetAsync(inv, 0, (size_t)nN * sizeof(float), stream);
    count_kernel<<<(nE + 255) / 256, 256, 0, stream>>>(dst, inv, nE);
    invert_kernel<<<(nN + 255) / 256, 256, 0, stream>>>(inv, nN);

    // ---- layer 1: aggregate x (32ch) then transform to 64
    hipMemsetAsync(agg, 0, (size_t)nN * 32 * sizeof(float), stream);
    scatter_kernel<32><<<(nE * 8 + 255) / 256, 256, 0, stream>>>(x, src, dst, agg, nE);
    xform_kernel<32, 32, 64, 64, 4, true, false, true, true>
        <<<dim3((nN + 63) / 64, 1), 256, 0, stream>>>(
            agg, x, w1l, w1r, b1, inv, nullptr, h1, nN);

    // ---- layer 2: aggregate h1 (64ch) then transform to 128
    hipMemsetAsync(agg, 0, (size_t)nN * 64 * sizeof(float), stream);
    scatter_kernel<64><<<(nE * 16 + 255) / 256, 256, 0, stream>>>(h1, src, dst, agg, nE);
    xform_kernel<64, 64, 128, 64, 2, true, false, true, true>
        <<<dim3((nN + 31) / 32, 2), 256, 0, stream>>>(
            agg, h1, w2l, w2r, b2, inv, nullptr, h2, nN);

    // ---- layer 3: transform h2 by w3_l first (64ch), aggregate, then add h2@w3_r
    xform_kernel<128, 0, 64, 64, 2, false, false, false, false>
        <<<dim3((nN + 31) / 32, 1), 256, 0, stream>>>(
            h2, nullptr, w3l, nullptr, nullptr, nullptr, nullptr, t3, nN);
    hipMemsetAsync(agg, 0, (size_t)nN * 64 * sizeof(float), stream);
    scatter_kernel<64><<<(nE * 16 + 255) / 256, 256, 0, stream>>>(t3, src, dst, agg, nE);
    xform_kernel<128, 0, 64, 64, 2, false, true, true, false>
        <<<dim3((nN + 31) / 32, 1), 256, 0, stream>>>(
            h2, nullptr, w3r, nullptr, b3, inv, agg, (float*)d_out, nN);
}

// Round 2
// 303.735 us; speedup vs baseline: 4.9990x; 4.9990x over previous
//
#include <hip/hip_runtime.h>

// ---------------------------------------------------------------------------
// GraphSAGE 3-layer encoder, fp32. N=50000, E=640000, ch 32 -> 64 -> 128 -> 64.
// R2: scatter-atomic aggregation (1.37ms of memory-side fp32 atomics) replaced
// by on-the-fly CSR build + gather-mean (deterministic-read, cache-resident).
// Layer 3 still transforms before aggregating (mean is linear; 64ch not 128ch).
// ---------------------------------------------------------------------------

__global__ void count_kernel(const int* __restrict__ dst, int* __restrict__ cnt, int nE) {
    int e = blockIdx.x * blockDim.x + threadIdx.x;
    if (e < nE) atomicAdd(&cnt[dst[e]], 1);
}

// single-block exclusive scan of cnt[0..nN) -> rowptr[0..nN]
__global__ __launch_bounds__(1024) void scan_kernel(const int* __restrict__ cnt,
                                                    int* __restrict__ rowptr, int nN) {
    __shared__ int lds[1024];
    const int t = threadIdx.x;
    const int chunk = (nN + 1023) >> 10;
    const int beg = t * chunk;
    const int end = min(beg + chunk, nN);
    int s = 0;
    for (int i = beg; i < end; ++i) s += cnt[i];
    lds[t] = s;
    __syncthreads();
    for (int d = 1; d < 1024; d <<= 1) {
        int v = (t >= d) ? lds[t - d] : 0;
        __syncthreads();
        lds[t] += v;
        __syncthreads();
    }
    int off = lds[t] - s;                      // exclusive prefix
    for (int i = beg; i < end; ++i) { rowptr[i] = off; off += cnt[i]; }
    if (t == 1023) rowptr[nN] = lds[1023];
}

__global__ void fill_kernel(const int* __restrict__ src, const int* __restrict__ dst,
                            const int* __restrict__ rowptr, int* __restrict__ cursor,
                            int* __restrict__ csr_src, int nE) {
    int e = blockIdx.x * blockDim.x + threadIdx.x;
    if (e < nE) {
        int d = dst[e];
        int pos = atomicAdd(&cursor[d], 1);
        csr_src[rowptr[d] + pos] = src[e];
    }
}

// agg[i] = mean_{j in N(i)} x[j]  (0 for empty neighborhoods)
// VPE = D/4 lanes per node, each owns one float4 column slice.
template<int D>
__global__ __launch_bounds__(256) void gather_mean_kernel(
    const float* __restrict__ x, const int* __restrict__ rowptr,
    const int* __restrict__ csr_src, float* __restrict__ agg, int nN)
{
    constexpr int VPE = D / 4;
    constexpr int NPB = 256 / VPE;
    const int tid = threadIdx.x;
    const int node = blockIdx.x * NPB + tid / VPE;
    const int c = tid % VPE;
    if (node >= nN) return;
    const int beg = rowptr[node];
    const int end = rowptr[node + 1];
    const float4* x4 = reinterpret_cast<const float4*>(x);
    float4 acc = make_float4(0.f, 0.f, 0.f, 0.f);
    int e = beg;
    // 2-deep manual pipeline for a little ILP on the random row reads
    for (; e + 1 < end; e += 2) {
        int s0 = csr_src[e];
        int s1 = csr_src[e + 1];
        float4 v0 = x4[(size_t)s0 * VPE + c];
        float4 v1 = x4[(size_t)s1 * VPE + c];
        acc.x += v0.x + v1.x; acc.y += v0.y + v1.y;
        acc.z += v0.z + v1.z; acc.w += v0.w + v1.w;
    }
    if (e < end) {
        int s0 = csr_src[e];
        float4 v0 = x4[(size_t)s0 * VPE + c];
        acc.x += v0.x; acc.y += v0.y; acc.z += v0.z; acc.w += v0.w;
    }
    const float sc = 1.0f / (float)max(end - beg, 1);
    acc.x *= sc; acc.y *= sc; acc.z *= sc; acc.w *= sc;
    reinterpret_cast<float4*>(agg)[(size_t)node * VPE + c] = acc;
}

// out[i, oc0:oc0+OCB] = act( [r0[i] | r1[i]] @ [w0 ; w1] + bias + aggadd[i] )
template<int D0, int D1, int DOUT, int OCB, int CN, bool ADDAGG, bool BIAS, bool RELU>
__global__ __launch_bounds__(256) void xform_kernel(
    const float* __restrict__ r0, const float* __restrict__ r1,
    const float* __restrict__ w0, const float* __restrict__ w1,
    const float* __restrict__ bias, const float* __restrict__ aggadd,
    float* __restrict__ out, int nNodes)
{
    constexpr int K = D0 + D1;
    constexpr int OCG = OCB / 4;
    constexpr int NG = 256 / OCG;
    constexpr int NT = NG * CN;
    constexpr int RSTRIDE = K + 4;

    __shared__ float wl[K * OCB];
    __shared__ float rows[NT * RSTRIDE];

    const int tid = threadIdx.x;
    const int node0 = blockIdx.x * NT;
    const int oc0 = blockIdx.y * OCB;

    {   // stage weight columns
        float4* wl4 = reinterpret_cast<float4*>(wl);
        const float4* w04 = reinterpret_cast<const float4*>(w0);
        constexpr int C = OCB / 4;
        for (int idx = tid; idx < D0 * C; idx += 256) {
            int k = idx / C, c = idx % C;
            wl4[idx] = w04[(size_t)k * (DOUT / 4) + oc0 / 4 + c];
        }
        if constexpr (D1 > 0) {
            const float4* w14 = reinterpret_cast<const float4*>(w1);
            for (int idx = tid; idx < D1 * C; idx += 256) {
                int k = idx / C, c = idx % C;
                wl4[D0 * C + idx] = w14[(size_t)k * (DOUT / 4) + oc0 / 4 + c];
            }
        }
    }
    {   // stage node rows [r0 | r1]
        constexpr int C4 = K / 4;
        const float4* r04 = reinterpret_cast<const float4*>(r0);
        for (int idx = tid; idx < NT * C4; idx += 256) {
            int n = idx / C4, c4 = idx % C4;
            int node = node0 + n;
            float4 v = make_float4(0.f, 0.f, 0.f, 0.f);
            if (node < nNodes) {
                if (D1 == 0 || c4 < D0 / 4) {
                    v = r04[(size_t)node * (D0 / 4) + c4];
                } else if constexpr (D1 > 0) {
                    const float4* r14 = reinterpret_cast<const float4*>(r1);
                    v = r14[(size_t)node * (D1 / 4) + (c4 - D0 / 4)];
                }
            }
            *reinterpret_cast<float4*>(&rows[n * RSTRIDE + c4 * 4]) = v;
        }
    }
    __syncthreads();

    const int ocg = tid % OCG;
    const int ng = tid / OCG;

    float acc[CN][4];
#pragma unroll
    for (int i = 0; i < CN; ++i) { acc[i][0] = acc[i][1] = acc[i][2] = acc[i][3] = 0.f; }

    const float4* wl4 = reinterpret_cast<const float4*>(wl);
#pragma unroll 4
    for (int k = 0; k < K; ++k) {
        float4 wv = wl4[k * OCG + ocg];
#pragma unroll
        for (int i = 0; i < CN; ++i) {
            float rv = rows[(ng * CN + i) * RSTRIDE + k];
            acc[i][0] = fmaf(rv, wv.x, acc[i][0]);
            acc[i][1] = fmaf(rv, wv.y, acc[i][1]);
            acc[i][2] = fmaf(rv, wv.z, acc[i][2]);
            acc[i][3] = fmaf(rv, wv.w, acc[i][3]);
        }
    }

    const int oc = oc0 + ocg * 4;
#pragma unroll
    for (int i = 0; i < CN; ++i) {
        int node = node0 + ng * CN + i;
        if (node >= nNodes) continue;
        float4 o = make_float4(acc[i][0], acc[i][1], acc[i][2], acc[i][3]);
        if constexpr (BIAS) {
            o.x += bias[oc + 0]; o.y += bias[oc + 1];
            o.z += bias[oc + 2]; o.w += bias[oc + 3];
        }
        if constexpr (ADDAGG) {
            float4 a = reinterpret_cast<const float4*>(aggadd)[(size_t)node * (DOUT / 4) + oc / 4];
            o.x += a.x; o.y += a.y; o.z += a.z; o.w += a.w;
        }
        if constexpr (RELU) {
            o.x = fmaxf(o.x, 0.f); o.y = fmaxf(o.y, 0.f);
            o.z = fmaxf(o.z, 0.f); o.w = fmaxf(o.w, 0.f);
        }
        reinterpret_cast<float4*>(out)[(size_t)node * (DOUT / 4) + oc / 4] = o;
    }
}

extern "C" void kernel_launch(void* const* d_in, const int* in_sizes, int n_in,
                              void* d_out, int out_size, void* d_ws, size_t ws_size,
                              hipStream_t stream) {
    const float* x   = (const float*)d_in[0];
    const int*   ei  = (const int*)d_in[1];
    const float* w1l = (const float*)d_in[2];
    const float* b1  = (const float*)d_in[3];
    const float* w1r = (const float*)d_in[4];
    const float* w2l = (const float*)d_in[5];
    const float* b2  = (const float*)d_in[6];
    const float* w2r = (const float*)d_in[7];
    const float* w3l = (const float*)d_in[8];
    const float* b3  = (const float*)d_in[9];
    const float* w3r = (const float*)d_in[10];

    const int nN = in_sizes[0] / 32;   // 50000
    const int nE = in_sizes[1] / 2;    // 640000
    const int* src = ei;
    const int* dst = ei + nE;

    char* ws = (char*)d_ws;
    size_t o = 0;
    auto alloc = [&](size_t nbytes) {
        char* p = ws + o;
        o += (nbytes + 255) & ~(size_t)255;
        return p;
    };
    int*   cnt     = (int*)alloc((size_t)nN * 2 * sizeof(int));   // cnt + cursor, adjacent
    int*   cursor  = cnt + ((size_t)nN + 32);                      // inside same zeroed span
    int*   rowptr  = (int*)alloc(((size_t)nN + 1) * sizeof(int));
    int*   csr_src = (int*)alloc((size_t)nE * sizeof(int));
    float* agg     = (float*)alloc((size_t)nN * 64 * sizeof(float));
    float* h1      = (float*)alloc((size_t)nN * 64 * sizeof(float));
    float* h2      = (float*)alloc((size_t)nN * 128 * sizeof(float));
    float* t3      = h1;   // h1 dead once h2 computed

    // ---- CSR build (shared by all layers)
    hipMemsetAsync(cnt, 0, ((size_t)nN * 2 + 64) * sizeof(int), stream);
    count_kernel<<<(nE + 255) / 256, 256, 0, stream>>>(dst, cnt, nE);
    scan_kernel<<<1, 1024, 0, stream>>>(cnt, rowptr, nN);
    fill_kernel<<<(nE + 255) / 256, 256, 0, stream>>>(src, dst, rowptr, cursor, csr_src, nE);

    // ---- layer 1: mean-aggregate x (32ch), transform [agg|x] -> 64, relu
    gather_mean_kernel<32><<<(nN + 31) / 32, 256, 0, stream>>>(x, rowptr, csr_src, agg, nN);
    xform_kernel<32, 32, 64, 64, 4, false, true, true>
        <<<dim3((nN + 63) / 64, 1), 256, 0, stream>>>(agg, x, w1l, w1r, b1, nullptr, h1, nN);

    // ---- layer 2: mean-aggregate h1 (64ch), transform [agg|h1] -> 128, relu
    gather_mean_kernel<64><<<(nN + 15) / 16, 256, 0, stream>>>(h1, rowptr, csr_src, agg, nN);
    xform_kernel<64, 64, 128, 64, 2, false, true, true>
        <<<dim3((nN + 31) / 32, 2), 256, 0, stream>>>(agg, h1, w2l, w2r, b2, nullptr, h2, nN);

    // ---- layer 3: t3 = h2@w3l (64ch), mean-aggregate t3, out = h2@w3r + b3 + agg
    xform_kernel<128, 0, 64, 64, 2, false, false, false>
        <<<dim3((nN + 31) / 32, 1), 256, 0, stream>>>(h2, nullptr, w3l, nullptr, nullptr, nullptr, t3, nN);
    gather_mean_kernel<64><<<(nN + 15) / 16, 256, 0, stream>>>(t3, rowptr, csr_src, agg, nN);
    xform_kernel<128, 0, 64, 64, 2, true, true, false>
        <<<dim3((nN + 31) / 32, 1), 256, 0, stream>>>(h2, nullptr, w3r, nullptr, b3, agg, (float*)d_out, nN);
}

// Round 3
// 234.488 us; speedup vs baseline: 6.4752x; 1.2953x over previous
//
#include <hip/hip_runtime.h>

// ---------------------------------------------------------------------------
// GraphSAGE 3-layer encoder, fp32. N=50000, E=640000, ch 32 -> 64 -> 128 -> 64.
// R3: single-block scan (76us, 0.15% occupancy) replaced by 3-stage
// hierarchical scan (~10us). CSR gather-mean aggregation as in R2.
// ---------------------------------------------------------------------------

__global__ void count_kernel(const int* __restrict__ dst, int* __restrict__ cnt, int nE) {
    int e = blockIdx.x * blockDim.x + threadIdx.x;
    if (e < nE) atomicAdd(&cnt[dst[e]], 1);
}

// Stage A: each block scans 1024 counts (256 thr x 4), writes exclusive scan
// into rowptr and its block total into partials[blockIdx].
__global__ __launch_bounds__(256) void scan_blocks(const int* __restrict__ cnt,
                                                   int* __restrict__ rowptr,
                                                   int* __restrict__ partials, int nN) {
    __shared__ int wsum[4];
    const int t = threadIdx.x;
    const int lane = t & 63, wid = t >> 6;
    const int base = blockIdx.x * 1024 + t * 4;

    int4 v = make_int4(0, 0, 0, 0);
    if (base + 3 < nN) {
        v = *reinterpret_cast<const int4*>(cnt + base);
    } else {
        if (base + 0 < nN) v.x = cnt[base + 0];
        if (base + 1 < nN) v.y = cnt[base + 1];
        if (base + 2 < nN) v.z = cnt[base + 2];
        if (base + 3 < nN) v.w = cnt[base + 3];
    }
    const int s = v.x + v.y + v.z + v.w;

    // wave-inclusive scan of s
    int inc = s;
#pragma unroll
    for (int d = 1; d < 64; d <<= 1) {
        int u = __shfl_up(inc, d);
        if (lane >= d) inc += u;
    }
    if (lane == 63) wsum[wid] = inc;
    __syncthreads();
    int woff = 0;
#pragma unroll
    for (int w = 0; w < 4; ++w) woff += (w < wid) ? wsum[w] : 0;

    const int excl = woff + inc - s;
    int4 o;
    o.x = excl;
    o.y = excl + v.x;
    o.z = excl + v.x + v.y;
    o.w = excl + v.x + v.y + v.z;
    if (base + 3 < nN) {
        *reinterpret_cast<int4*>(rowptr + base) = o;
    } else {
        if (base + 0 < nN) rowptr[base + 0] = o.x;
        if (base + 1 < nN) rowptr[base + 1] = o.y;
        if (base + 2 < nN) rowptr[base + 2] = o.z;
        if (base + 3 < nN) rowptr[base + 3] = o.w;
    }
    if (t == 255) partials[blockIdx.x] = woff + inc;   // block total
}

// Stage B: one wave exclusive-scans the block partials (nB <= 64).
__global__ __launch_bounds__(64) void scan_partials(int* __restrict__ partials, int nB) {
    const int t = threadIdx.x;
    int v = (t < nB) ? partials[t] : 0;
    int inc = v;
#pragma unroll
    for (int d = 1; d < 64; d <<= 1) {
        int u = __shfl_up(inc, d);
        if (t >= d) inc += u;
    }
    if (t < nB) partials[t] = inc - v;                 // exclusive
}

// Stage C: add block offsets; write rowptr[nN] = nE.
__global__ __launch_bounds__(256) void scan_add(int* __restrict__ rowptr,
                                                const int* __restrict__ partials,
                                                int nN, int nE) {
    const int off = partials[blockIdx.x];
    const int base = blockIdx.x * 1024 + threadIdx.x * 4;
    if (base + 3 < nN) {
        int4 v = *reinterpret_cast<int4*>(rowptr + base);
        v.x += off; v.y += off; v.z += off; v.w += off;
        *reinterpret_cast<int4*>(rowptr + base) = v;
    } else {
        if (base + 0 < nN) rowptr[base + 0] += off;
        if (base + 1 < nN) rowptr[base + 1] += off;
        if (base + 2 < nN) rowptr[base + 2] += off;
        if (base + 3 < nN) rowptr[base + 3] += off;
    }
    if (blockIdx.x == 0 && threadIdx.x == 0) rowptr[nN] = nE;
}

__global__ void fill_kernel(const int* __restrict__ src, const int* __restrict__ dst,
                            const int* __restrict__ rowptr, int* __restrict__ cursor,
                            int* __restrict__ csr_src, int nE) {
    int e = blockIdx.x * blockDim.x + threadIdx.x;
    if (e < nE) {
        int d = dst[e];
        int pos = atomicAdd(&cursor[d], 1);
        csr_src[rowptr[d] + pos] = src[e];
    }
}

// agg[i] = mean_{j in N(i)} x[j]  (0 for empty neighborhoods)
template<int D>
__global__ __launch_bounds__(256) void gather_mean_kernel(
    const float* __restrict__ x, const int* __restrict__ rowptr,
    const int* __restrict__ csr_src, float* __restrict__ agg, int nN)
{
    constexpr int VPE = D / 4;
    constexpr int NPB = 256 / VPE;
    const int tid = threadIdx.x;
    const int node = blockIdx.x * NPB + tid / VPE;
    const int c = tid % VPE;
    if (node >= nN) return;
    const int beg = rowptr[node];
    const int end = rowptr[node + 1];
    const float4* x4 = reinterpret_cast<const float4*>(x);
    float4 acc = make_float4(0.f, 0.f, 0.f, 0.f);
    int e = beg;
    for (; e + 1 < end; e += 2) {
        int s0 = csr_src[e];
        int s1 = csr_src[e + 1];
        float4 v0 = x4[(size_t)s0 * VPE + c];
        float4 v1 = x4[(size_t)s1 * VPE + c];
        acc.x += v0.x + v1.x; acc.y += v0.y + v1.y;
        acc.z += v0.z + v1.z; acc.w += v0.w + v1.w;
    }
    if (e < end) {
        int s0 = csr_src[e];
        float4 v0 = x4[(size_t)s0 * VPE + c];
        acc.x += v0.x; acc.y += v0.y; acc.z += v0.z; acc.w += v0.w;
    }
    const float sc = 1.0f / (float)max(end - beg, 1);
    acc.x *= sc; acc.y *= sc; acc.z *= sc; acc.w *= sc;
    reinterpret_cast<float4*>(agg)[(size_t)node * VPE + c] = acc;
}

// out[i, oc0:oc0+OCB] = act( [r0[i] | r1[i]] @ [w0 ; w1] + bias + aggadd[i] )
template<int D0, int D1, int DOUT, int OCB, int CN, bool ADDAGG, bool BIAS, bool RELU>
__global__ __launch_bounds__(256) void xform_kernel(
    const float* __restrict__ r0, const float* __restrict__ r1,
    const float* __restrict__ w0, const float* __restrict__ w1,
    const float* __restrict__ bias, const float* __restrict__ aggadd,
    float* __restrict__ out, int nNodes)
{
    constexpr int K = D0 + D1;
    constexpr int OCG = OCB / 4;
    constexpr int NG = 256 / OCG;
    constexpr int NT = NG * CN;
    constexpr int RSTRIDE = K + 4;

    __shared__ float wl[K * OCB];
    __shared__ float rows[NT * RSTRIDE];

    const int tid = threadIdx.x;
    const int node0 = blockIdx.x * NT;
    const int oc0 = blockIdx.y * OCB;

    {   // stage weight columns
        float4* wl4 = reinterpret_cast<float4*>(wl);
        const float4* w04 = reinterpret_cast<const float4*>(w0);
        constexpr int C = OCB / 4;
        for (int idx = tid; idx < D0 * C; idx += 256) {
            int k = idx / C, c = idx % C;
            wl4[idx] = w04[(size_t)k * (DOUT / 4) + oc0 / 4 + c];
        }
        if constexpr (D1 > 0) {
            const float4* w14 = reinterpret_cast<const float4*>(w1);
            for (int idx = tid; idx < D1 * C; idx += 256) {
                int k = idx / C, c = idx % C;
                wl4[D0 * C + idx] = w14[(size_t)k * (DOUT / 4) + oc0 / 4 + c];
            }
        }
    }
    {   // stage node rows [r0 | r1]
        constexpr int C4 = K / 4;
        const float4* r04 = reinterpret_cast<const float4*>(r0);
        for (int idx = tid; idx < NT * C4; idx += 256) {
            int n = idx / C4, c4 = idx % C4;
            int node = node0 + n;
            float4 v = make_float4(0.f, 0.f, 0.f, 0.f);
            if (node < nNodes) {
                if (D1 == 0 || c4 < D0 / 4) {
                    v = r04[(size_t)node * (D0 / 4) + c4];
                } else if constexpr (D1 > 0) {
                    const float4* r14 = reinterpret_cast<const float4*>(r1);
                    v = r14[(size_t)node * (D1 / 4) + (c4 - D0 / 4)];
                }
            }
            *reinterpret_cast<float4*>(&rows[n * RSTRIDE + c4 * 4]) = v;
        }
    }
    __syncthreads();

    const int ocg = tid % OCG;
    const int ng = tid / OCG;

    float acc[CN][4];
#pragma unroll
    for (int i = 0; i < CN; ++i) { acc[i][0] = acc[i][1] = acc[i][2] = acc[i][3] = 0.f; }

    const float4* wl4 = reinterpret_cast<const float4*>(wl);
#pragma unroll 4
    for (int k = 0; k < K; ++k) {
        float4 wv = wl4[k * OCG + ocg];
#pragma unroll
        for (int i = 0; i < CN; ++i) {
            float rv = rows[(ng * CN + i) * RSTRIDE + k];
            acc[i][0] = fmaf(rv, wv.x, acc[i][0]);
            acc[i][1] = fmaf(rv, wv.y, acc[i][1]);
            acc[i][2] = fmaf(rv, wv.z, acc[i][2]);
            acc[i][3] = fmaf(rv, wv.w, acc[i][3]);
        }
    }

    const int oc = oc0 + ocg * 4;
#pragma unroll
    for (int i = 0; i < CN; ++i) {
        int node = node0 + ng * CN + i;
        if (node >= nNodes) continue;
        float4 o = make_float4(acc[i][0], acc[i][1], acc[i][2], acc[i][3]);
        if constexpr (BIAS) {
            o.x += bias[oc + 0]; o.y += bias[oc + 1];
            o.z += bias[oc + 2]; o.w += bias[oc + 3];
        }
        if constexpr (ADDAGG) {
            float4 a = reinterpret_cast<const float4*>(aggadd)[(size_t)node * (DOUT / 4) + oc / 4];
            o.x += a.x; o.y += a.y; o.z += a.z; o.w += a.w;
        }
        if constexpr (RELU) {
            o.x = fmaxf(o.x, 0.f); o.y = fmaxf(o.y, 0.f);
            o.z = fmaxf(o.z, 0.f); o.w = fmaxf(o.w, 0.f);
        }
        reinterpret_cast<float4*>(out)[(size_t)node * (DOUT / 4) + oc / 4] = o;
    }
}

extern "C" void kernel_launch(void* const* d_in, const int* in_sizes, int n_in,
                              void* d_out, int out_size, void* d_ws, size_t ws_size,
                              hipStream_t stream) {
    const float* x   = (const float*)d_in[0];
    const int*   ei  = (const int*)d_in[1];
    const float* w1l = (const float*)d_in[2];
    const float* b1  = (const float*)d_in[3];
    const float* w1r = (const float*)d_in[4];
    const float* w2l = (const float*)d_in[5];
    const float* b2  = (const float*)d_in[6];
    const float* w2r = (const float*)d_in[7];
    const float* w3l = (const float*)d_in[8];
    const float* b3  = (const float*)d_in[9];
    const float* w3r = (const float*)d_in[10];

    const int nN = in_sizes[0] / 32;   // 50000
    const int nE = in_sizes[1] / 2;    // 640000
    const int* src = ei;
    const int* dst = ei + nE;
    const int nB = (nN + 1023) / 1024; // scan blocks (49 <= 64)

    char* ws = (char*)d_ws;
    size_t o = 0;
    auto alloc = [&](size_t nbytes) {
        char* p = ws + o;
        o += (nbytes + 255) & ~(size_t)255;
        return p;
    };
    int*   cnt      = (int*)alloc(((size_t)nN * 2 + 64) * sizeof(int)); // cnt + cursor
    int*   cursor   = cnt + nN + 32;
    int*   partials = (int*)alloc(64 * sizeof(int));
    int*   rowptr   = (int*)alloc(((size_t)nN + 1) * sizeof(int));
    int*   csr_src  = (int*)alloc((size_t)nE * sizeof(int));
    float* agg      = (float*)alloc((size_t)nN * 64 * sizeof(float));
    float* h1       = (float*)alloc((size_t)nN * 64 * sizeof(float));
    float* h2       = (float*)alloc((size_t)nN * 128 * sizeof(float));
    float* t3       = h1;   // h1 dead once h2 computed

    // ---- CSR build (shared by all layers)
    hipMemsetAsync(cnt, 0, ((size_t)nN * 2 + 64) * sizeof(int), stream);
    count_kernel<<<(nE + 255) / 256, 256, 0, stream>>>(dst, cnt, nE);
    scan_blocks<<<nB, 256, 0, stream>>>(cnt, rowptr, partials, nN);
    scan_partials<<<1, 64, 0, stream>>>(partials, nB);
    scan_add<<<nB, 256, 0, stream>>>(rowptr, partials, nN, nE);
    fill_kernel<<<(nE + 255) / 256, 256, 0, stream>>>(src, dst, rowptr, cursor, csr_src, nE);

    // ---- layer 1: mean-aggregate x (32ch), transform [agg|x] -> 64, relu
    gather_mean_kernel<32><<<(nN + 31) / 32, 256, 0, stream>>>(x, rowptr, csr_src, agg, nN);
    xform_kernel<32, 32, 64, 64, 4, false, true, true>
        <<<dim3((nN + 63) / 64, 1), 256, 0, stream>>>(agg, x, w1l, w1r, b1, nullptr, h1, nN);

    // ---- layer 2: mean-aggregate h1 (64ch), transform [agg|h1] -> 128, relu
    gather_mean_kernel<64><<<(nN + 15) / 16, 256, 0, stream>>>(h1, rowptr, csr_src, agg, nN);
    xform_kernel<64, 64, 128, 64, 2, false, true, true>
        <<<dim3((nN + 31) / 32, 2), 256, 0, stream>>>(agg, h1, w2l, w2r, b2, nullptr, h2, nN);

    // ---- layer 3: t3 = h2@w3l (64ch), mean-aggregate t3, out = h2@w3r + b3 + agg
    xform_kernel<128, 0, 64, 64, 2, false, false, false>
        <<<dim3((nN + 31) / 32, 1), 256, 0, stream>>>(h2, nullptr, w3l, nullptr, nullptr, nullptr, t3, nN);
    gather_mean_kernel<64><<<(nN + 15) / 16, 256, 0, stream>>>(t3, rowptr, csr_src, agg, nN);
    xform_kernel<128, 0, 64, 64, 2, true, true, false>
        <<<dim3((nN + 31) / 32, 1), 256, 0, stream>>>(h2, nullptr, w3r, nullptr, b3, agg, (float*)d_out, nN);
}

// Round 4
// 232.725 us; speedup vs baseline: 6.5243x; 1.0076x over previous
//
#include <hip/hip_runtime.h>

// ---------------------------------------------------------------------------
// GraphSAGE 3-layer encoder, fp32. N=50000, E=640000, ch 32 -> 64 -> 128 -> 64.
// R4: (a) runtime memset (44us) -> own zero_kernel; (b) xform restructured:
// rows streamed global->reg (sequential, L1-coalesced), only weights in LDS
// (32KB -> 5 blocks/CU occupancy, 16 FMA per 2 mem ops); (c) layer-3 fused:
// one DUAL dispatch does h2@w3l and h2@w3r+b3, final gather adds r3 -> d_out.
// ---------------------------------------------------------------------------

__global__ void zero_kernel(int4* __restrict__ p, int n4) {
    int i = blockIdx.x * blockDim.x + threadIdx.x;
    if (i < n4) p[i] = make_int4(0, 0, 0, 0);
}

__global__ void count_kernel(const int* __restrict__ dst, int* __restrict__ cnt, int nE) {
    int e = blockIdx.x * blockDim.x + threadIdx.x;
    if (e < nE) atomicAdd(&cnt[dst[e]], 1);
}

// Stage A: each block scans 1024 counts (256 thr x 4) -> rowptr, block total -> partials
__global__ __launch_bounds__(256) void scan_blocks(const int* __restrict__ cnt,
                                                   int* __restrict__ rowptr,
                                                   int* __restrict__ partials, int nN) {
    __shared__ int wsum[4];
    const int t = threadIdx.x;
    const int lane = t & 63, wid = t >> 6;
    const int base = blockIdx.x * 1024 + t * 4;

    int4 v = make_int4(0, 0, 0, 0);
    if (base + 3 < nN) {
        v = *reinterpret_cast<const int4*>(cnt + base);
    } else {
        if (base + 0 < nN) v.x = cnt[base + 0];
        if (base + 1 < nN) v.y = cnt[base + 1];
        if (base + 2 < nN) v.z = cnt[base + 2];
        if (base + 3 < nN) v.w = cnt[base + 3];
    }
    const int s = v.x + v.y + v.z + v.w;

    int inc = s;
#pragma unroll
    for (int d = 1; d < 64; d <<= 1) {
        int u = __shfl_up(inc, d);
        if (lane >= d) inc += u;
    }
    if (lane == 63) wsum[wid] = inc;
    __syncthreads();
    int woff = 0;
#pragma unroll
    for (int w = 0; w < 4; ++w) woff += (w < wid) ? wsum[w] : 0;

    const int excl = woff + inc - s;
    int4 o;
    o.x = excl;
    o.y = excl + v.x;
    o.z = excl + v.x + v.y;
    o.w = excl + v.x + v.y + v.z;
    if (base + 3 < nN) {
        *reinterpret_cast<int4*>(rowptr + base) = o;
    } else {
        if (base + 0 < nN) rowptr[base + 0] = o.x;
        if (base + 1 < nN) rowptr[base + 1] = o.y;
        if (base + 2 < nN) rowptr[base + 2] = o.z;
        if (base + 3 < nN) rowptr[base + 3] = o.w;
    }
    if (t == 255) partials[blockIdx.x] = woff + inc;
}

__global__ __launch_bounds__(64) void scan_partials(int* __restrict__ partials, int nB) {
    const int t = threadIdx.x;
    int v = (t < nB) ? partials[t] : 0;
    int inc = v;
#pragma unroll
    for (int d = 1; d < 64; d <<= 1) {
        int u = __shfl_up(inc, d);
        if (t >= d) inc += u;
    }
    if (t < nB) partials[t] = inc - v;
}

__global__ __launch_bounds__(256) void scan_add(int* __restrict__ rowptr,
                                                const int* __restrict__ partials,
                                                int nN, int nE) {
    const int off = partials[blockIdx.x];
    const int base = blockIdx.x * 1024 + threadIdx.x * 4;
    if (base + 3 < nN) {
        int4 v = *reinterpret_cast<int4*>(rowptr + base);
        v.x += off; v.y += off; v.z += off; v.w += off;
        *reinterpret_cast<int4*>(rowptr + base) = v;
    } else {
        if (base + 0 < nN) rowptr[base + 0] += off;
        if (base + 1 < nN) rowptr[base + 1] += off;
        if (base + 2 < nN) rowptr[base + 2] += off;
        if (base + 3 < nN) rowptr[base + 3] += off;
    }
    if (blockIdx.x == 0 && threadIdx.x == 0) rowptr[nN] = nE;
}

__global__ void fill_kernel(const int* __restrict__ src, const int* __restrict__ dst,
                            const int* __restrict__ rowptr, int* __restrict__ cursor,
                            int* __restrict__ csr_src, int nE) {
    int e = blockIdx.x * blockDim.x + threadIdx.x;
    if (e < nE) {
        int d = dst[e];
        int pos = atomicAdd(&cursor[d], 1);
        csr_src[rowptr[d] + pos] = src[e];
    }
}

// out[i] = (ADD ? addsrc[i] : 0) + mean_{j in N(i)} x[j]
template<int D, bool ADD>
__global__ __launch_bounds__(256) void gather_mean_kernel(
    const float* __restrict__ x, const int* __restrict__ rowptr,
    const int* __restrict__ csr_src, const float* __restrict__ addsrc,
    float* __restrict__ outp, int nN)
{
    constexpr int VPE = D / 4;
    constexpr int NPB = 256 / VPE;
    const int tid = threadIdx.x;
    const int node = blockIdx.x * NPB + tid / VPE;
    const int c = tid % VPE;
    if (node >= nN) return;
    const int beg = rowptr[node];
    const int end = rowptr[node + 1];
    const float4* x4 = reinterpret_cast<const float4*>(x);
    float4 acc = make_float4(0.f, 0.f, 0.f, 0.f);
    int e = beg;
    for (; e + 3 < end; e += 4) {
        int s0 = csr_src[e + 0], s1 = csr_src[e + 1];
        int s2 = csr_src[e + 2], s3 = csr_src[e + 3];
        float4 v0 = x4[(size_t)s0 * VPE + c];
        float4 v1 = x4[(size_t)s1 * VPE + c];
        float4 v2 = x4[(size_t)s2 * VPE + c];
        float4 v3 = x4[(size_t)s3 * VPE + c];
        acc.x += (v0.x + v1.x) + (v2.x + v3.x);
        acc.y += (v0.y + v1.y) + (v2.y + v3.y);
        acc.z += (v0.z + v1.z) + (v2.z + v3.z);
        acc.w += (v0.w + v1.w) + (v2.w + v3.w);
    }
    for (; e < end; ++e) {
        int s0 = csr_src[e];
        float4 v0 = x4[(size_t)s0 * VPE + c];
        acc.x += v0.x; acc.y += v0.y; acc.z += v0.z; acc.w += v0.w;
    }
    const float sc = 1.0f / (float)max(end - beg, 1);
    float4 o = make_float4(acc.x * sc, acc.y * sc, acc.z * sc, acc.w * sc);
    if constexpr (ADD) {
        float4 a = reinterpret_cast<const float4*>(addsrc)[(size_t)node * VPE + c];
        o.x += a.x; o.y += a.y; o.z += a.z; o.w += a.w;
    }
    reinterpret_cast<float4*>(outp)[(size_t)node * VPE + c] = o;
}

// GEMM: out = [r0 | r1] @ [w0 ; w1] (+bias) (+relu). Rows streamed from global
// (registers), weights staged in LDS. 256 thr: 16 col-groups (4 cols each) x
// 16 node-groups x CN nodes. Non-DUAL: blockIdx.y picks output col block.
// DUAL: blockIdx.y=0 -> w0/out0 (no bias), =1 -> w1/out1 (+bias if BIAS).
template<int K, int D0, int OCB, int CN, bool DUAL, bool BIAS, bool RELU>
__global__ __launch_bounds__(256) void xform_kernel(
    const float* __restrict__ r0, const float* __restrict__ r1,
    const float* __restrict__ w0, const float* __restrict__ w1,
    int wstride, const float* __restrict__ bias,
    float* __restrict__ out0, float* __restrict__ out1,
    int ostride, int nN)
{
    constexpr int C4 = OCB / 4;       // float4 cols per block
    constexpr int OCG = C4;           // 16 col groups
    constexpr int NG = 256 / OCG;     // 16 node groups
    constexpr int NT = NG * CN;       // nodes per block
    constexpr int KC = K / 4;
    constexpr int D0C = D0 / 4;

    __shared__ float4 wl4[K * C4];

    const int tid = threadIdx.x;
    const int sel = blockIdx.y;
    const int oc0 = DUAL ? 0 : sel * OCB;
    float* __restrict__ outp = (DUAL && sel) ? out1 : out0;

    // ---- stage weights [K][OCB]
    for (int idx = tid; idx < K * C4; idx += 256) {
        int k = idx / C4, c = idx % C4;
        const float* wrow;
        if constexpr (DUAL) {
            wrow = (sel ? w1 : w0) + (size_t)k * wstride;
        } else {
            wrow = (k < D0) ? (w0 + (size_t)k * wstride)
                            : (w1 + (size_t)(k - D0) * wstride);
        }
        wl4[idx] = *reinterpret_cast<const float4*>(wrow + oc0 + 4 * c);
    }
    __syncthreads();

    const int ocg = tid % OCG;
    const int ng  = tid / OCG;
    const int nodeBase = blockIdx.x * NT + ng * CN;

    int nd[CN];
#pragma unroll
    for (int i = 0; i < CN; ++i) nd[i] = min(nodeBase + i, nN - 1);

    const float4* r04 = reinterpret_cast<const float4*>(r0);
    const float4* r14 = reinterpret_cast<const float4*>(r1);

    float4 acc[CN];
#pragma unroll
    for (int i = 0; i < CN; ++i) acc[i] = make_float4(0.f, 0.f, 0.f, 0.f);

    auto step = [&](int kc, const float4 (&rv)[CN]) {
        float4 wv0 = wl4[(4 * kc + 0) * C4 + ocg];
        float4 wv1 = wl4[(4 * kc + 1) * C4 + ocg];
        float4 wv2 = wl4[(4 * kc + 2) * C4 + ocg];
        float4 wv3 = wl4[(4 * kc + 3) * C4 + ocg];
#pragma unroll
        for (int i = 0; i < CN; ++i) {
            acc[i].x = fmaf(rv[i].x, wv0.x, acc[i].x);
            acc[i].y = fmaf(rv[i].x, wv0.y, acc[i].y);
            acc[i].z = fmaf(rv[i].x, wv0.z, acc[i].z);
            acc[i].w = fmaf(rv[i].x, wv0.w, acc[i].w);
            acc[i].x = fmaf(rv[i].y, wv1.x, acc[i].x);
            acc[i].y = fmaf(rv[i].y, wv1.y, acc[i].y);
            acc[i].z = fmaf(rv[i].y, wv1.z, acc[i].z);
            acc[i].w = fmaf(rv[i].y, wv1.w, acc[i].w);
            acc[i].x = fmaf(rv[i].z, wv2.x, acc[i].x);
            acc[i].y = fmaf(rv[i].z, wv2.y, acc[i].y);
            acc[i].z = fmaf(rv[i].z, wv2.z, acc[i].z);
            acc[i].w = fmaf(rv[i].z, wv2.w, acc[i].w);
            acc[i].x = fmaf(rv[i].w, wv3.x, acc[i].x);
            acc[i].y = fmaf(rv[i].w, wv3.y, acc[i].y);
            acc[i].z = fmaf(rv[i].w, wv3.z, acc[i].z);
            acc[i].w = fmaf(rv[i].w, wv3.w, acc[i].w);
        }
    };

#pragma unroll 4
    for (int kc = 0; kc < D0C; ++kc) {
        float4 rv[CN];
#pragma unroll
        for (int i = 0; i < CN; ++i) rv[i] = r04[(size_t)nd[i] * D0C + kc];
        step(kc, rv);
    }
    if constexpr (D0C < KC) {
        constexpr int D1C = KC - D0C;
#pragma unroll 4
        for (int kc = D0C; kc < KC; ++kc) {
            float4 rv[CN];
#pragma unroll
            for (int i = 0; i < CN; ++i) rv[i] = r14[(size_t)nd[i] * D1C + (kc - D0C)];
            step(kc, rv);
        }
    }

    float4 bv = make_float4(0.f, 0.f, 0.f, 0.f);
    if constexpr (BIAS) {
        if (!DUAL || sel)
            bv = *reinterpret_cast<const float4*>(bias + oc0 + 4 * ocg);
    }
    float4* out4 = reinterpret_cast<float4*>(outp);
    const int oc4 = oc0 / 4 + ocg;
    const int os4 = ostride / 4;
#pragma unroll
    for (int i = 0; i < CN; ++i) {
        int node = nodeBase + i;
        if (node >= nN) break;
        float4 o = acc[i];
        o.x += bv.x; o.y += bv.y; o.z += bv.z; o.w += bv.w;
        if constexpr (RELU) {
            o.x = fmaxf(o.x, 0.f); o.y = fmaxf(o.y, 0.f);
            o.z = fmaxf(o.z, 0.f); o.w = fmaxf(o.w, 0.f);
        }
        out4[(size_t)node * os4 + oc4] = o;
    }
}

extern "C" void kernel_launch(void* const* d_in, const int* in_sizes, int n_in,
                              void* d_out, int out_size, void* d_ws, size_t ws_size,
                              hipStream_t stream) {
    const float* x   = (const float*)d_in[0];
    const int*   ei  = (const int*)d_in[1];
    const float* w1l = (const float*)d_in[2];
    const float* b1  = (const float*)d_in[3];
    const float* w1r = (const float*)d_in[4];
    const float* w2l = (const float*)d_in[5];
    const float* b2  = (const float*)d_in[6];
    const float* w2r = (const float*)d_in[7];
    const float* w3l = (const float*)d_in[8];
    const float* b3  = (const float*)d_in[9];
    const float* w3r = (const float*)d_in[10];

    const int nN = in_sizes[0] / 32;   // 50000
    const int nE = in_sizes[1] / 2;    // 640000
    const int* src = ei;
    const int* dst = ei + nE;
    const int nB = (nN + 1023) / 1024; // 49 scan blocks

    char* ws = (char*)d_ws;
    size_t o = 0;
    auto alloc = [&](size_t nbytes) {
        char* p = ws + o;
        o += (nbytes + 255) & ~(size_t)255;
        return p;
    };
    int*   cnt      = (int*)alloc(((size_t)nN * 2 + 64) * sizeof(int)); // cnt + cursor
    int*   cursor   = cnt + nN + 32;
    int*   partials = (int*)alloc(64 * sizeof(int));
    int*   rowptr   = (int*)alloc(((size_t)nN + 1) * sizeof(int));
    int*   csr_src  = (int*)alloc((size_t)nE * sizeof(int));
    float* agg      = (float*)alloc((size_t)nN * 64 * sizeof(float));
    float* h1       = (float*)alloc((size_t)nN * 64 * sizeof(float));
    float* h2       = (float*)alloc((size_t)nN * 128 * sizeof(float));
    float* t3       = h1;    // h1 dead after layer-2 xform
    float* r3       = agg;   // agg dead after layer-2 xform

    const int nzero4 = (int)(((size_t)nN * 2 + 64) / 4);

    // ---- CSR build
    zero_kernel<<<(nzero4 + 255) / 256, 256, 0, stream>>>((int4*)cnt, nzero4);
    count_kernel<<<(nE + 255) / 256, 256, 0, stream>>>(dst, cnt, nE);
    scan_blocks<<<nB, 256, 0, stream>>>(cnt, rowptr, partials, nN);
    scan_partials<<<1, 64, 0, stream>>>(partials, nB);
    scan_add<<<nB, 256, 0, stream>>>(rowptr, partials, nN, nE);
    fill_kernel<<<(nE + 255) / 256, 256, 0, stream>>>(src, dst, rowptr, cursor, csr_src, nE);

    const int xblk = (nN + 63) / 64;   // NT = 16*CN = 64

    // ---- layer 1: agg = mean(x), h1 = relu([agg|x] @ [w1l;w1r] + b1)
    gather_mean_kernel<32, false><<<(nN + 31) / 32, 256, 0, stream>>>(
        x, rowptr, csr_src, nullptr, agg, nN);
    xform_kernel<64, 32, 64, 4, false, true, true><<<dim3(xblk, 1), 256, 0, stream>>>(
        agg, x, w1l, w1r, 64, b1, h1, nullptr, 64, nN);

    // ---- layer 2: agg = mean(h1), h2 = relu([agg|h1] @ [w2l;w2r] + b2)
    gather_mean_kernel<64, false><<<(nN + 15) / 16, 256, 0, stream>>>(
        h1, rowptr, csr_src, nullptr, agg, nN);
    xform_kernel<128, 64, 64, 4, false, true, true><<<dim3(xblk, 2), 256, 0, stream>>>(
        agg, h1, w2l, w2r, 128, b2, h2, nullptr, 128, nN);

    // ---- layer 3 (fused): t3 = h2@w3l, r3 = h2@w3r + b3; out = r3 + mean(t3)
    xform_kernel<128, 128, 64, 4, true, true, false><<<dim3(xblk, 2), 256, 0, stream>>>(
        h2, nullptr, w3l, w3r, 64, b3, t3, r3, 64, nN);
    gather_mean_kernel<64, true><<<(nN + 15) / 16, 256, 0, stream>>>(
        t3, rowptr, csr_src, r3, (float*)d_out, nN);
}

// Round 5
// 194.077 us; speedup vs baseline: 7.8235x; 1.1991x over previous
//
#include <hip/hip_runtime.h>

// ---------------------------------------------------------------------------
// GraphSAGE 3-layer encoder. N=50000, E=640000, ch 32 -> 64 -> 128 -> 64.
// R5: GEMMs moved to split-bf16 MFMA (a = a_hi + a_lo; 3 MFMA per k-chunk:
// hi*hi + hi*lo + lo*hi, fp32 accumulate) -> fp32-grade accuracy at matrix-
// core rate. CSR build + gather-mean aggregation unchanged from R4.
// ---------------------------------------------------------------------------

typedef short bf8 __attribute__((ext_vector_type(8)));   // 8 bf16 in 4 VGPR
typedef float f32x4 __attribute__((ext_vector_type(4)));

__device__ inline ushort bf16rn(float f) {               // round-to-nearest-even
    unsigned u = __float_as_uint(f);
    return (ushort)((u + 0x7FFFu + ((u >> 16) & 1u)) >> 16);
}
__device__ inline float bf16tof(ushort h) {
    return __uint_as_float(((unsigned)h) << 16);
}

__global__ void zero_kernel(int4* __restrict__ p, int n4) {
    int i = blockIdx.x * blockDim.x + threadIdx.x;
    if (i < n4) p[i] = make_int4(0, 0, 0, 0);
}

__global__ void count_kernel(const int* __restrict__ dst, int* __restrict__ cnt, int nE) {
    int e = blockIdx.x * blockDim.x + threadIdx.x;
    if (e < nE) atomicAdd(&cnt[dst[e]], 1);
}

__global__ __launch_bounds__(256) void scan_blocks(const int* __restrict__ cnt,
                                                   int* __restrict__ rowptr,
                                                   int* __restrict__ partials, int nN) {
    __shared__ int wsum[4];
    const int t = threadIdx.x;
    const int lane = t & 63, wid = t >> 6;
    const int base = blockIdx.x * 1024 + t * 4;

    int4 v = make_int4(0, 0, 0, 0);
    if (base + 3 < nN) {
        v = *reinterpret_cast<const int4*>(cnt + base);
    } else {
        if (base + 0 < nN) v.x = cnt[base + 0];
        if (base + 1 < nN) v.y = cnt[base + 1];
        if (base + 2 < nN) v.z = cnt[base + 2];
        if (base + 3 < nN) v.w = cnt[base + 3];
    }
    const int s = v.x + v.y + v.z + v.w;

    int inc = s;
#pragma unroll
    for (int d = 1; d < 64; d <<= 1) {
        int u = __shfl_up(inc, d);
        if (lane >= d) inc += u;
    }
    if (lane == 63) wsum[wid] = inc;
    __syncthreads();
    int woff = 0;
#pragma unroll
    for (int w = 0; w < 4; ++w) woff += (w < wid) ? wsum[w] : 0;

    const int excl = woff + inc - s;
    int4 o;
    o.x = excl;
    o.y = excl + v.x;
    o.z = excl + v.x + v.y;
    o.w = excl + v.x + v.y + v.z;
    if (base + 3 < nN) {
        *reinterpret_cast<int4*>(rowptr + base) = o;
    } else {
        if (base + 0 < nN) rowptr[base + 0] = o.x;
        if (base + 1 < nN) rowptr[base + 1] = o.y;
        if (base + 2 < nN) rowptr[base + 2] = o.z;
        if (base + 3 < nN) rowptr[base + 3] = o.w;
    }
    if (t == 255) partials[blockIdx.x] = woff + inc;
}

__global__ __launch_bounds__(64) void scan_partials(int* __restrict__ partials, int nB) {
    const int t = threadIdx.x;
    int v = (t < nB) ? partials[t] : 0;
    int inc = v;
#pragma unroll
    for (int d = 1; d < 64; d <<= 1) {
        int u = __shfl_up(inc, d);
        if (t >= d) inc += u;
    }
    if (t < nB) partials[t] = inc - v;
}

__global__ __launch_bounds__(256) void scan_add(int* __restrict__ rowptr,
                                                const int* __restrict__ partials,
                                                int nN, int nE) {
    const int off = partials[blockIdx.x];
    const int base = blockIdx.x * 1024 + threadIdx.x * 4;
    if (base + 3 < nN) {
        int4 v = *reinterpret_cast<int4*>(rowptr + base);
        v.x += off; v.y += off; v.z += off; v.w += off;
        *reinterpret_cast<int4*>(rowptr + base) = v;
    } else {
        if (base + 0 < nN) rowptr[base + 0] += off;
        if (base + 1 < nN) rowptr[base + 1] += off;
        if (base + 2 < nN) rowptr[base + 2] += off;
        if (base + 3 < nN) rowptr[base + 3] += off;
    }
    if (blockIdx.x == 0 && threadIdx.x == 0) rowptr[nN] = nE;
}

__global__ void fill_kernel(const int* __restrict__ src, const int* __restrict__ dst,
                            const int* __restrict__ rowptr, int* __restrict__ cursor,
                            int* __restrict__ csr_src, int nE) {
    int e = blockIdx.x * blockDim.x + threadIdx.x;
    if (e < nE) {
        int d = dst[e];
        int pos = atomicAdd(&cursor[d], 1);
        csr_src[rowptr[d] + pos] = src[e];
    }
}

// out[i] = (ADD ? addsrc[i] : 0) + mean_{j in N(i)} x[j]
template<int D, bool ADD>
__global__ __launch_bounds__(256) void gather_mean_kernel(
    const float* __restrict__ x, const int* __restrict__ rowptr,
    const int* __restrict__ csr_src, const float* __restrict__ addsrc,
    float* __restrict__ outp, int nN)
{
    constexpr int VPE = D / 4;
    constexpr int NPB = 256 / VPE;
    const int tid = threadIdx.x;
    const int node = blockIdx.x * NPB + tid / VPE;
    const int c = tid % VPE;
    if (node >= nN) return;
    const int beg = rowptr[node];
    const int end = rowptr[node + 1];
    const float4* x4 = reinterpret_cast<const float4*>(x);
    float4 acc = make_float4(0.f, 0.f, 0.f, 0.f);
    int e = beg;
    for (; e + 3 < end; e += 4) {
        int s0 = csr_src[e + 0], s1 = csr_src[e + 1];
        int s2 = csr_src[e + 2], s3 = csr_src[e + 3];
        float4 v0 = x4[(size_t)s0 * VPE + c];
        float4 v1 = x4[(size_t)s1 * VPE + c];
        float4 v2 = x4[(size_t)s2 * VPE + c];
        float4 v3 = x4[(size_t)s3 * VPE + c];
        acc.x += (v0.x + v1.x) + (v2.x + v3.x);
        acc.y += (v0.y + v1.y) + (v2.y + v3.y);
        acc.z += (v0.z + v1.z) + (v2.z + v3.z);
        acc.w += (v0.w + v1.w) + (v2.w + v3.w);
    }
    for (; e < end; ++e) {
        int s0 = csr_src[e];
        float4 v0 = x4[(size_t)s0 * VPE + c];
        acc.x += v0.x; acc.y += v0.y; acc.z += v0.z; acc.w += v0.w;
    }
    const float sc = 1.0f / (float)max(end - beg, 1);
    float4 o = make_float4(acc.x * sc, acc.y * sc, acc.z * sc, acc.w * sc);
    if constexpr (ADD) {
        float4 a = reinterpret_cast<const float4*>(addsrc)[(size_t)node * VPE + c];
        o.x += a.x; o.y += a.y; o.z += a.z; o.w += a.w;
    }
    reinterpret_cast<float4*>(outp)[(size_t)node * VPE + c] = o;
}

// ---------------------------------------------------------------------------
// Split-bf16 MFMA GEMM: out = concat(r0, r1) @ W (+bias) (+relu)
// Block = 256 thr = 4 waves; wave w owns rows [blk*64 + w*16, +16), cols 0..63
// of the y-selected 64-col block, as 4 16x16 tiles via mfma_f32_16x16x32_bf16.
// Weights pre-split (hi/lo bf16) into LDS as ready-to-read 16B fragments:
//   wlds[ct][kc][s][lane][8], lane = kgroup*16 + col  (B: k=(l>>4)*8+j, col=l&15)
// A: lane reads row (l&15), k = kc*32 + (l>>4)*8 .. +8 (2 float4), splits hi/lo.
// 3 MFMA per k-chunk: hi*hi + hi*lo + lo*hi (fp32 acc; alo*blo ~2^-17, dropped).
// C/D layout (m89-verified): col = lane&15, row = (lane>>4)*4 + reg.
// ---------------------------------------------------------------------------
template<int K, int D0, bool DUAL, bool BIAS, bool RELU>
__global__ __launch_bounds__(256) void mfma_xform(
    const float* __restrict__ r0, const float* __restrict__ r1,
    const float* __restrict__ w0, const float* __restrict__ w1,
    int wstride, const float* __restrict__ bias,
    float* __restrict__ out0, float* __restrict__ out1,
    int ostride, int nN)
{
    constexpr int KC = K / 32;                       // 32-wide k chunks
    __shared__ ushort wlds[4 * KC * 2 * 64 * 8];     // 16KB (K=64) / 32KB (K=128)

    const int tid = threadIdx.x;
    const int sel = blockIdx.y;
    const int oc0 = DUAL ? 0 : sel * 64;
    const float* __restrict__ wd = DUAL ? (sel ? w1 : w0) : w0;
    float* __restrict__ outp = (DUAL && sel) ? out1 : out0;

    // ---- stage weights, split hi/lo, fragment layout
    for (int idx = tid; idx < 64 * (K / 8); idx += 256) {
        const int g = idx >> 6;        // 8-k group
        const int c = idx & 63;        // col in 64-block
        float v[8];
#pragma unroll
        for (int j = 0; j < 8; ++j) {
            const int k = g * 8 + j;
            const float* wr;
            if constexpr (DUAL) {
                wr = wd + (size_t)k * wstride;
            } else {
                wr = (k < D0) ? (w0 + (size_t)k * wstride)
                              : (w1 + (size_t)(k - D0) * wstride);
            }
            v[j] = wr[oc0 + c];
        }
        const int ct = c >> 4, colin = c & 15;
        const int kc = g >> 2, kg = g & 3;
        const int lane = kg * 16 + colin;
        ushort* hp = &wlds[(((ct * KC + kc) * 2 + 0) * 64 + lane) * 8];
        ushort* lp = hp + 64 * 8;
#pragma unroll
        for (int j = 0; j < 8; ++j) {
            ushort h = bf16rn(v[j]);
            hp[j] = h;
            lp[j] = bf16rn(v[j] - bf16tof(h));
        }
    }
    __syncthreads();

    const int w = tid >> 6;
    const int lane = tid & 63;
    const int row0 = blockIdx.x * 64 + w * 16;
    const int arow = min(row0 + (lane & 15), nN - 1);
    const int kg = lane >> 4;

    // ---- load + split A fragments (held in registers across all col tiles)
    bf8 ahi[KC], alo[KC];
#pragma unroll
    for (int kc = 0; kc < KC; ++kc) {
        const int k0 = kc * 32 + kg * 8;
        const float* rp;
        int kk;
        if (k0 < D0) { rp = r0 + (size_t)arow * D0; kk = k0; }
        else         { rp = r1 + (size_t)arow * (K - D0); kk = k0 - D0; }
        const float4 p = *reinterpret_cast<const float4*>(rp + kk);
        const float4 q = *reinterpret_cast<const float4*>(rp + kk + 4);
        const float v[8] = {p.x, p.y, p.z, p.w, q.x, q.y, q.z, q.w};
        bf8 A, L;
#pragma unroll
        for (int j = 0; j < 8; ++j) {
            const ushort h = bf16rn(v[j]);
            A[j] = (short)h;
            L[j] = (short)bf16rn(v[j] - bf16tof(h));
        }
        ahi[kc] = A;
        alo[kc] = L;
    }

    // ---- 4 col tiles x KC chunks x 3 split-MFMAs
    const bf8* bl = reinterpret_cast<const bf8*>(wlds);
#pragma unroll
    for (int ct = 0; ct < 4; ++ct) {
        f32x4 acc = {0.f, 0.f, 0.f, 0.f};
#pragma unroll
        for (int kc = 0; kc < KC; ++kc) {
            const bf8 bhi = bl[((ct * KC + kc) * 2 + 0) * 64 + lane];
            const bf8 blo = bl[((ct * KC + kc) * 2 + 1) * 64 + lane];
            acc = __builtin_amdgcn_mfma_f32_16x16x32_bf16(ahi[kc], bhi, acc, 0, 0, 0);
            acc = __builtin_amdgcn_mfma_f32_16x16x32_bf16(ahi[kc], blo, acc, 0, 0, 0);
            acc = __builtin_amdgcn_mfma_f32_16x16x32_bf16(alo[kc], bhi, acc, 0, 0, 0);
        }
        const int col = oc0 + ct * 16 + (lane & 15);
        float bv = 0.f;
        if (BIAS && (!DUAL || sel)) bv = bias[col];
#pragma unroll
        for (int r = 0; r < 4; ++r) {
            const int node = row0 + (lane >> 4) * 4 + r;
            if (node < nN) {
                float o = acc[r] + bv;
                if constexpr (RELU) o = fmaxf(o, 0.f);
                outp[(size_t)node * ostride + col] = o;
            }
        }
    }
}

extern "C" void kernel_launch(void* const* d_in, const int* in_sizes, int n_in,
                              void* d_out, int out_size, void* d_ws, size_t ws_size,
                              hipStream_t stream) {
    const float* x   = (const float*)d_in[0];
    const int*   ei  = (const int*)d_in[1];
    const float* w1l = (const float*)d_in[2];
    const float* b1  = (const float*)d_in[3];
    const float* w1r = (const float*)d_in[4];
    const float* w2l = (const float*)d_in[5];
    const float* b2  = (const float*)d_in[6];
    const float* w2r = (const float*)d_in[7];
    const float* w3l = (const float*)d_in[8];
    const float* b3  = (const float*)d_in[9];
    const float* w3r = (const float*)d_in[10];

    const int nN = in_sizes[0] / 32;   // 50000
    const int nE = in_sizes[1] / 2;    // 640000
    const int* src = ei;
    const int* dst = ei + nE;
    const int nB = (nN + 1023) / 1024; // 49 scan blocks

    char* ws = (char*)d_ws;
    size_t o = 0;
    auto alloc = [&](size_t nbytes) {
        char* p = ws + o;
        o += (nbytes + 255) & ~(size_t)255;
        return p;
    };
    int*   cnt      = (int*)alloc(((size_t)nN * 2 + 64) * sizeof(int)); // cnt + cursor
    int*   cursor   = cnt + nN + 32;
    int*   partials = (int*)alloc(64 * sizeof(int));
    int*   rowptr   = (int*)alloc(((size_t)nN + 1) * sizeof(int));
    int*   csr_src  = (int*)alloc((size_t)nE * sizeof(int));
    float* agg      = (float*)alloc((size_t)nN * 64 * sizeof(float));
    float* h1       = (float*)alloc((size_t)nN * 64 * sizeof(float));
    float* h2       = (float*)alloc((size_t)nN * 128 * sizeof(float));
    float* t3       = h1;    // h1 dead after layer-2 xform
    float* r3       = agg;   // agg dead after layer-2 xform

    const int nzero4 = (int)(((size_t)nN * 2 + 64) / 4);

    // ---- CSR build
    zero_kernel<<<(nzero4 + 255) / 256, 256, 0, stream>>>((int4*)cnt, nzero4);
    count_kernel<<<(nE + 255) / 256, 256, 0, stream>>>(dst, cnt, nE);
    scan_blocks<<<nB, 256, 0, stream>>>(cnt, rowptr, partials, nN);
    scan_partials<<<1, 64, 0, stream>>>(partials, nB);
    scan_add<<<nB, 256, 0, stream>>>(rowptr, partials, nN, nE);
    fill_kernel<<<(nE + 255) / 256, 256, 0, stream>>>(src, dst, rowptr, cursor, csr_src, nE);

    const int xblk = (nN + 63) / 64;   // 64 rows per block

    // ---- layer 1: agg = mean(x); h1 = relu([agg|x] @ [w1l;w1r] + b1)
    gather_mean_kernel<32, false><<<(nN + 31) / 32, 256, 0, stream>>>(
        x, rowptr, csr_src, nullptr, agg, nN);
    mfma_xform<64, 32, false, true, true><<<dim3(xblk, 1), 256, 0, stream>>>(
        agg, x, w1l, w1r, 64, b1, h1, nullptr, 64, nN);

    // ---- layer 2: agg = mean(h1); h2 = relu([agg|h1] @ [w2l;w2r] + b2)
    gather_mean_kernel<64, false><<<(nN + 15) / 16, 256, 0, stream>>>(
        h1, rowptr, csr_src, nullptr, agg, nN);
    mfma_xform<128, 64, false, true, true><<<dim3(xblk, 2), 256, 0, stream>>>(
        agg, h1, w2l, w2r, 128, b2, h2, nullptr, 128, nN);

    // ---- layer 3 (fused): t3 = h2@w3l; r3 = h2@w3r + b3; out = r3 + mean(t3)
    mfma_xform<128, 128, true, true, false><<<dim3(xblk, 2), 256, 0, stream>>>(
        h2, nullptr, w3l, w3r, 64, b3, t3, r3, 64, nN);
    gather_mean_kernel<64, true><<<(nN + 15) / 16, 256, 0, stream>>>(
        t3, rowptr, csr_src, r3, (float*)d_out, nN);
}

// Round 6
// 187.058 us; speedup vs baseline: 8.1171x; 1.0375x over previous
//
#include <hip/hip_runtime.h>

// ---------------------------------------------------------------------------
// GraphSAGE 3-layer encoder. N=50000, E=640000, ch 32 -> 64 -> 128 -> 64.
// R6: (a) gathers: 8-deep index-prefetch + 8 row loads in flight (MLP);
// (b) count/fill: 4 edges/thread via int4; (c) scan_partials folded into
// scan_add (per-block wave reduce of partials); (d) weight hi/lo-bf16 split
// hoisted into a run-once prep_weights kernel -> xform stages via flat copy.
// GEMMs remain split-bf16 MFMA (hi*hi + hi*lo + lo*hi, fp32 acc).
// ---------------------------------------------------------------------------

typedef short bf8 __attribute__((ext_vector_type(8)));   // 8 bf16 in 4 VGPR
typedef float f32x4 __attribute__((ext_vector_type(4)));

__device__ inline ushort bf16rn(float f) {               // round-to-nearest-even
    unsigned u = __float_as_uint(f);
    return (ushort)((u + 0x7FFFu + ((u >> 16) & 1u)) >> 16);
}
__device__ inline float bf16tof(ushort h) {
    return __uint_as_float(((unsigned)h) << 16);
}

__global__ void zero_kernel(int4* __restrict__ p, int n4) {
    int i = blockIdx.x * blockDim.x + threadIdx.x;
    if (i < n4) p[i] = make_int4(0, 0, 0, 0);
}

__global__ __launch_bounds__(256) void count_kernel(const int* __restrict__ dst,
                                                    int* __restrict__ cnt, int nE) {
    int i = blockIdx.x * blockDim.x + threadIdx.x;
    int e0 = i * 4;
    if (e0 + 3 < nE) {
        int4 d = *reinterpret_cast<const int4*>(dst + e0);
        atomicAdd(&cnt[d.x], 1);
        atomicAdd(&cnt[d.y], 1);
        atomicAdd(&cnt[d.z], 1);
        atomicAdd(&cnt[d.w], 1);
    } else {
        for (int e = e0; e < nE; ++e) atomicAdd(&cnt[dst[e]], 1);
    }
}

// Stage A: each block scans 1024 counts (256 thr x 4) -> rowptr, total -> partials
__global__ __launch_bounds__(256) void scan_blocks(const int* __restrict__ cnt,
                                                   int* __restrict__ rowptr,
                                                   int* __restrict__ partials, int nN) {
    __shared__ int wsum[4];
    const int t = threadIdx.x;
    const int lane = t & 63, wid = t >> 6;
    const int base = blockIdx.x * 1024 + t * 4;

    int4 v = make_int4(0, 0, 0, 0);
    if (base + 3 < nN) {
        v = *reinterpret_cast<const int4*>(cnt + base);
    } else {
        if (base + 0 < nN) v.x = cnt[base + 0];
        if (base + 1 < nN) v.y = cnt[base + 1];
        if (base + 2 < nN) v.z = cnt[base + 2];
        if (base + 3 < nN) v.w = cnt[base + 3];
    }
    const int s = v.x + v.y + v.z + v.w;

    int inc = s;
#pragma unroll
    for (int d = 1; d < 64; d <<= 1) {
        int u = __shfl_up(inc, d);
        if (lane >= d) inc += u;
    }
    if (lane == 63) wsum[wid] = inc;
    __syncthreads();
    int woff = 0;
#pragma unroll
    for (int w = 0; w < 4; ++w) woff += (w < wid) ? wsum[w] : 0;

    const int excl = woff + inc - s;
    int4 o;
    o.x = excl;
    o.y = excl + v.x;
    o.z = excl + v.x + v.y;
    o.w = excl + v.x + v.y + v.z;
    if (base + 3 < nN) {
        *reinterpret_cast<int4*>(rowptr + base) = o;
    } else {
        if (base + 0 < nN) rowptr[base + 0] = o.x;
        if (base + 1 < nN) rowptr[base + 1] = o.y;
        if (base + 2 < nN) rowptr[base + 2] = o.z;
        if (base + 3 < nN) rowptr[base + 3] = o.w;
    }
    if (t == 255) partials[blockIdx.x] = woff + inc;
}

// Stage B (merged): each block reduces partials[0..blockIdx) itself, then adds.
__global__ __launch_bounds__(256) void scan_add(int* __restrict__ rowptr,
                                                const int* __restrict__ partials,
                                                int nN, int nE) {
    __shared__ int soff;
    const int t = threadIdx.x;
    if (t < 64) {
        int v = (t < blockIdx.x) ? partials[t] : 0;   // grid <= 64 blocks
#pragma unroll
        for (int d = 32; d >= 1; d >>= 1) v += __shfl_xor(v, d);
        if (t == 0) soff = v;
    }
    __syncthreads();
    const int off = soff;
    const int base = blockIdx.x * 1024 + t * 4;
    if (base + 3 < nN) {
        int4 v = *reinterpret_cast<int4*>(rowptr + base);
        v.x += off; v.y += off; v.z += off; v.w += off;
        *reinterpret_cast<int4*>(rowptr + base) = v;
    } else {
        if (base + 0 < nN) rowptr[base + 0] += off;
        if (base + 1 < nN) rowptr[base + 1] += off;
        if (base + 2 < nN) rowptr[base + 2] += off;
        if (base + 3 < nN) rowptr[base + 3] += off;
    }
    if (blockIdx.x == 0 && t == 0) rowptr[nN] = nE;
}

__global__ __launch_bounds__(256) void fill_kernel(const int* __restrict__ src,
                                                   const int* __restrict__ dst,
                                                   const int* __restrict__ rowptr,
                                                   int* __restrict__ cursor,
                                                   int* __restrict__ csr_src, int nE) {
    int i = blockIdx.x * blockDim.x + threadIdx.x;
    int e0 = i * 4;
    if (e0 + 3 < nE) {
        int4 s4 = *reinterpret_cast<const int4*>(src + e0);
        int4 d4 = *reinterpret_cast<const int4*>(dst + e0);
        int p0 = atomicAdd(&cursor[d4.x], 1); csr_src[rowptr[d4.x] + p0] = s4.x;
        int p1 = atomicAdd(&cursor[d4.y], 1); csr_src[rowptr[d4.y] + p1] = s4.y;
        int p2 = atomicAdd(&cursor[d4.z], 1); csr_src[rowptr[d4.z] + p2] = s4.z;
        int p3 = atomicAdd(&cursor[d4.w], 1); csr_src[rowptr[d4.w] + p3] = s4.w;
    } else {
        for (int e = e0; e < nE; ++e) {
            int d = dst[e];
            int pos = atomicAdd(&cursor[d], 1);
            csr_src[rowptr[d] + pos] = src[e];
        }
    }
}

// out[i] = (ADD ? addsrc[i] : 0) + mean_{j in N(i)} x[j]
template<int D, bool ADD>
__global__ __launch_bounds__(256) void gather_mean_kernel(
    const float* __restrict__ x, const int* __restrict__ rowptr,
    const int* __restrict__ csr_src, const float* __restrict__ addsrc,
    float* __restrict__ outp, int nN)
{
    constexpr int VPE = D / 4;
    constexpr int NPB = 256 / VPE;
    const int tid = threadIdx.x;
    const int node = blockIdx.x * NPB + tid / VPE;
    const int c = tid % VPE;
    if (node >= nN) return;
    const int beg = rowptr[node];
    const int end = rowptr[node + 1];
    const float4* x4 = reinterpret_cast<const float4*>(x);
    float4 acc = make_float4(0.f, 0.f, 0.f, 0.f);
    int e = beg;
    for (; e + 7 < end; e += 8) {               // 8 loads in flight
        int s[8];
#pragma unroll
        for (int j = 0; j < 8; ++j) s[j] = csr_src[e + j];
        float4 v[8];
#pragma unroll
        for (int j = 0; j < 8; ++j) v[j] = x4[(size_t)s[j] * VPE + c];
        acc.x += ((v[0].x + v[1].x) + (v[2].x + v[3].x)) + ((v[4].x + v[5].x) + (v[6].x + v[7].x));
        acc.y += ((v[0].y + v[1].y) + (v[2].y + v[3].y)) + ((v[4].y + v[5].y) + (v[6].y + v[7].y));
        acc.z += ((v[0].z + v[1].z) + (v[2].z + v[3].z)) + ((v[4].z + v[5].z) + (v[6].z + v[7].z));
        acc.w += ((v[0].w + v[1].w) + (v[2].w + v[3].w)) + ((v[4].w + v[5].w) + (v[6].w + v[7].w));
    }
    for (; e + 1 < end; e += 2) {
        int s0 = csr_src[e], s1 = csr_src[e + 1];
        float4 v0 = x4[(size_t)s0 * VPE + c];
        float4 v1 = x4[(size_t)s1 * VPE + c];
        acc.x += v0.x + v1.x; acc.y += v0.y + v1.y;
        acc.z += v0.z + v1.z; acc.w += v0.w + v1.w;
    }
    if (e < end) {
        int s0 = csr_src[e];
        float4 v0 = x4[(size_t)s0 * VPE + c];
        acc.x += v0.x; acc.y += v0.y; acc.z += v0.z; acc.w += v0.w;
    }
    const float sc = 1.0f / (float)max(end - beg, 1);
    float4 o = make_float4(acc.x * sc, acc.y * sc, acc.z * sc, acc.w * sc);
    if constexpr (ADD) {
        float4 a = reinterpret_cast<const float4*>(addsrc)[(size_t)node * VPE + c];
        o.x += a.x; o.y += a.y; o.z += a.z; o.w += a.w;
    }
    reinterpret_cast<float4*>(outp)[(size_t)node * VPE + c] = o;
}

// ---------------------------------------------------------------------------
// One-shot weight prep: split all 5 weight blocks into hi/lo bf16 fragments in
// the exact LDS layout mfma_xform consumes: frag f = ((ct*KC+kc)*2+s)*64+lane,
// holding 8 bf16 at k = kc*32+(lane>>4)*8+j, col = oc0+ct*16+(lane&15).
// Sections: [0,1024) L1 K=64 concat(w1l,w1r); [1024,3072) L2 cols 0-63;
// [3072,5120) L2 cols 64-127; [5120,7168) w3l; [7168,9216) w3r.
// ---------------------------------------------------------------------------
__global__ __launch_bounds__(256) void prep_weights(
    const float* __restrict__ w1l, const float* __restrict__ w1r,
    const float* __restrict__ w2l, const float* __restrict__ w2r,
    const float* __restrict__ w3l, const float* __restrict__ w3r,
    ushort* __restrict__ outw)
{
    const int f = blockIdx.x * 256 + threadIdx.x;   // 0..9215
    int base, KCs, oc0, d0, wstride;
    const float *wa, *wb;
    if (f < 1024)      { base = 0;    KCs = 2; oc0 = 0;  wa = w1l; wb = w1r; d0 = 32;  wstride = 64;  }
    else if (f < 3072) { base = 1024; KCs = 4; oc0 = 0;  wa = w2l; wb = w2r; d0 = 64;  wstride = 128; }
    else if (f < 5120) { base = 3072; KCs = 4; oc0 = 64; wa = w2l; wb = w2r; d0 = 64;  wstride = 128; }
    else if (f < 7168) { base = 5120; KCs = 4; oc0 = 0;  wa = w3l; wb = w3l; d0 = 128; wstride = 64;  }
    else               { base = 7168; KCs = 4; oc0 = 0;  wa = w3r; wb = w3r; d0 = 128; wstride = 64;  }
    const int local = f - base;
    const int lane = local & 63;
    const int s = (local >> 6) & 1;
    const int kcct = local >> 7;
    const int kc = kcct % KCs;
    const int ct = kcct / KCs;
    const int col = oc0 + ct * 16 + (lane & 15);
    const int k0 = kc * 32 + (lane >> 4) * 8;
    ushort h8[8];
#pragma unroll
    for (int j = 0; j < 8; ++j) {
        const int k = k0 + j;
        const float* wr = (k < d0) ? (wa + (size_t)k * wstride)
                                   : (wb + (size_t)(k - d0) * wstride);
        const float v = wr[col];
        const ushort h = bf16rn(v);
        h8[j] = (s == 0) ? h : bf16rn(v - bf16tof(h));
    }
    *reinterpret_cast<int4*>(outw + (size_t)f * 8) = *reinterpret_cast<const int4*>(h8);
}

// ---------------------------------------------------------------------------
// Split-bf16 MFMA GEMM: out = concat(r0, r1) @ W (+bias) (+relu)
// Weights arrive pre-split/pre-laid (prep_weights); staging = flat int4 copy.
// Block = 4 waves; wave w owns rows [blk*64+w*16, +16) x 64 cols as 4 tiles.
// 3 MFMA per 32-k chunk: hi*hi + hi*lo + lo*hi (fp32 acc).
// C/D layout (m89-verified): col = lane&15, row = (lane>>4)*4 + reg.
// ---------------------------------------------------------------------------
template<int K, int D0, bool DUAL, bool BIAS, bool RELU>
__global__ __launch_bounds__(256) void mfma_xform(
    const float* __restrict__ r0, const float* __restrict__ r1,
    const ushort* __restrict__ wfrag, const float* __restrict__ bias,
    float* __restrict__ out0, float* __restrict__ out1,
    int ostride, int nN)
{
    constexpr int KC = K / 32;                       // 32-wide k chunks
    constexpr int NFRAG = 4 * KC * 2 * 64;           // fragments per col-block
    __shared__ ushort wlds[NFRAG * 8];               // 16KB (K=64) / 32KB (K=128)

    const int tid = threadIdx.x;
    const int sel = blockIdx.y;
    const int oc0 = DUAL ? 0 : sel * 64;
    float* __restrict__ outp = (DUAL && sel) ? out1 : out0;

    // ---- stage pre-split weights: flat 16B copy
    {
        const int4* wsrc = reinterpret_cast<const int4*>(wfrag) + (size_t)sel * NFRAG;
        int4* wl = reinterpret_cast<int4*>(wlds);
        for (int idx = tid; idx < NFRAG; idx += 256) wl[idx] = wsrc[idx];
    }
    __syncthreads();

    const int w = tid >> 6;
    const int lane = tid & 63;
    const int row0 = blockIdx.x * 64 + w * 16;
    const int arow = min(row0 + (lane & 15), nN - 1);
    const int kg = lane >> 4;

    // ---- load + split A fragments
    bf8 ahi[KC], alo[KC];
#pragma unroll
    for (int kc = 0; kc < KC; ++kc) {
        const int k0 = kc * 32 + kg * 8;
        const float* rp;
        int kk;
        if (k0 < D0) { rp = r0 + (size_t)arow * D0; kk = k0; }
        else         { rp = r1 + (size_t)arow * (K - D0); kk = k0 - D0; }
        const float4 p = *reinterpret_cast<const float4*>(rp + kk);
        const float4 q = *reinterpret_cast<const float4*>(rp + kk + 4);
        const float v[8] = {p.x, p.y, p.z, p.w, q.x, q.y, q.z, q.w};
        bf8 A, L;
#pragma unroll
        for (int j = 0; j < 8; ++j) {
            const ushort h = bf16rn(v[j]);
            A[j] = (short)h;
            L[j] = (short)bf16rn(v[j] - bf16tof(h));
        }
        ahi[kc] = A;
        alo[kc] = L;
    }

    // ---- 4 col tiles x KC chunks x 3 split-MFMAs
    const bf8* bl = reinterpret_cast<const bf8*>(wlds);
#pragma unroll
    for (int ct = 0; ct < 4; ++ct) {
        f32x4 acc = {0.f, 0.f, 0.f, 0.f};
#pragma unroll
        for (int kc = 0; kc < KC; ++kc) {
            const bf8 bhi = bl[((ct * KC + kc) * 2 + 0) * 64 + lane];
            const bf8 blo = bl[((ct * KC + kc) * 2 + 1) * 64 + lane];
            acc = __builtin_amdgcn_mfma_f32_16x16x32_bf16(ahi[kc], bhi, acc, 0, 0, 0);
            acc = __builtin_amdgcn_mfma_f32_16x16x32_bf16(ahi[kc], blo, acc, 0, 0, 0);
            acc = __builtin_amdgcn_mfma_f32_16x16x32_bf16(alo[kc], bhi, acc, 0, 0, 0);
        }
        const int col = oc0 + ct * 16 + (lane & 15);
        float bv = 0.f;
        if (BIAS && (!DUAL || sel)) bv = bias[col];
#pragma unroll
        for (int r = 0; r < 4; ++r) {
            const int node = row0 + (lane >> 4) * 4 + r;
            if (node < nN) {
                float o = acc[r] + bv;
                if constexpr (RELU) o = fmaxf(o, 0.f);
                outp[(size_t)node * ostride + col] = o;
            }
        }
    }
}

extern "C" void kernel_launch(void* const* d_in, const int* in_sizes, int n_in,
                              void* d_out, int out_size, void* d_ws, size_t ws_size,
                              hipStream_t stream) {
    const float* x   = (const float*)d_in[0];
    const int*   ei  = (const int*)d_in[1];
    const float* w1l = (const float*)d_in[2];
    const float* b1  = (const float*)d_in[3];
    const float* w1r = (const float*)d_in[4];
    const float* w2l = (const float*)d_in[5];
    const float* b2  = (const float*)d_in[6];
    const float* w2r = (const float*)d_in[7];
    const float* w3l = (const float*)d_in[8];
    const float* b3  = (const float*)d_in[9];
    const float* w3r = (const float*)d_in[10];

    const int nN = in_sizes[0] / 32;   // 50000
    const int nE = in_sizes[1] / 2;    // 640000
    const int* src = ei;
    const int* dst = ei + nE;
    const int nB = (nN + 1023) / 1024; // 49 scan blocks (<= 64)

    char* ws = (char*)d_ws;
    size_t o = 0;
    auto alloc = [&](size_t nbytes) {
        char* p = ws + o;
        o += (nbytes + 255) & ~(size_t)255;
        return p;
    };
    int*    cnt      = (int*)alloc(((size_t)nN * 2 + 64) * sizeof(int)); // cnt + cursor
    int*    cursor   = cnt + nN + 32;
    int*    partials = (int*)alloc(64 * sizeof(int));
    int*    rowptr   = (int*)alloc(((size_t)nN + 1) * sizeof(int));
    int*    csr_src  = (int*)alloc((size_t)nE * sizeof(int));
    ushort* wprep    = (ushort*)alloc((size_t)9216 * 8 * sizeof(ushort)); // 144KB
    float*  agg      = (float*)alloc((size_t)nN * 64 * sizeof(float));
    float*  h1       = (float*)alloc((size_t)nN * 64 * sizeof(float));
    float*  h2       = (float*)alloc((size_t)nN * 128 * sizeof(float));
    float*  t3       = h1;    // h1 dead after layer-2 xform
    float*  r3       = agg;   // agg dead after layer-2 xform

    const int nzero4 = (int)(((size_t)nN * 2 + 64) / 4);

    // ---- weight prep (independent of edges)
    prep_weights<<<36, 256, 0, stream>>>(w1l, w1r, w2l, w2r, w3l, w3r, wprep);

    // ---- CSR build
    zero_kernel<<<(nzero4 + 255) / 256, 256, 0, stream>>>((int4*)cnt, nzero4);
    count_kernel<<<(nE / 4 + 255) / 256, 256, 0, stream>>>(dst, cnt, nE);
    scan_blocks<<<nB, 256, 0, stream>>>(cnt, rowptr, partials, nN);
    scan_add<<<nB, 256, 0, stream>>>(rowptr, partials, nN, nE);
    fill_kernel<<<(nE / 4 + 255) / 256, 256, 0, stream>>>(src, dst, rowptr, cursor, csr_src, nE);

    const int xblk = (nN + 63) / 64;   // 64 rows per block

    // ---- layer 1: agg = mean(x); h1 = relu([agg|x] @ [w1l;w1r] + b1)
    gather_mean_kernel<32, false><<<(nN + 31) / 32, 256, 0, stream>>>(
        x, rowptr, csr_src, nullptr, agg, nN);
    mfma_xform<64, 32, false, true, true><<<dim3(xblk, 1), 256, 0, stream>>>(
        agg, x, wprep, b1, h1, nullptr, 64, nN);

    // ---- layer 2: agg = mean(h1); h2 = relu([agg|h1] @ [w2l;w2r] + b2)
    gather_mean_kernel<64, false><<<(nN + 15) / 16, 256, 0, stream>>>(
        h1, rowptr, csr_src, nullptr, agg, nN);
    mfma_xform<128, 64, false, true, true><<<dim3(xblk, 2), 256, 0, stream>>>(
        agg, h1, wprep + (size_t)1024 * 8, b2, h2, nullptr, 128, nN);

    // ---- layer 3 (fused): t3 = h2@w3l; r3 = h2@w3r + b3; out = r3 + mean(t3)
    mfma_xform<128, 128, true, true, false><<<dim3(xblk, 2), 256, 0, stream>>>(
        h2, nullptr, wprep + (size_t)5120 * 8, b3, t3, r3, 64, nN);
    gather_mean_kernel<64, true><<<(nN + 15) / 16, 256, 0, stream>>>(
        t3, rowptr, csr_src, r3, (float*)d_out, nN);
}

// Round 7
// 179.760 us; speedup vs baseline: 8.4467x; 1.0406x over previous
//
#include <hip/hip_runtime.h>

// ---------------------------------------------------------------------------
// GraphSAGE 3-layer encoder. N=50000, E=640000, ch 32 -> 64 -> 128 -> 64.
// R7: gather fused INTO the GEMMs for layers 1-2 (block gathers its 64 rows'
// neighborhoods into an LDS f32 tile, then split-bf16 MFMA with A=[tile|self]).
// Removes 2 launches + agg global round-trip; overlaps gather latency with
// MFMA across resident blocks. L2-fused reads B-fragments from L1-hot wprep
// (no 64KB LDS staging). Layer 3 DUAL GEMM + final gather+add unchanged.
// ---------------------------------------------------------------------------

typedef short bf8 __attribute__((ext_vector_type(8)));   // 8 bf16 in 4 VGPR
typedef float f32x4 __attribute__((ext_vector_type(4)));

__device__ inline ushort bf16rn(float f) {               // round-to-nearest-even
    unsigned u = __float_as_uint(f);
    return (ushort)((u + 0x7FFFu + ((u >> 16) & 1u)) >> 16);
}
__device__ inline float bf16tof(ushort h) {
    return __uint_as_float(((unsigned)h) << 16);
}

__global__ void zero_kernel(int4* __restrict__ p, int n4) {
    int i = blockIdx.x * blockDim.x + threadIdx.x;
    if (i < n4) p[i] = make_int4(0, 0, 0, 0);
}

__global__ __launch_bounds__(256) void count_kernel(const int* __restrict__ dst,
                                                    int* __restrict__ cnt, int nE) {
    int i = blockIdx.x * blockDim.x + threadIdx.x;
    int e0 = i * 4;
    if (e0 + 3 < nE) {
        int4 d = *reinterpret_cast<const int4*>(dst + e0);
        atomicAdd(&cnt[d.x], 1);
        atomicAdd(&cnt[d.y], 1);
        atomicAdd(&cnt[d.z], 1);
        atomicAdd(&cnt[d.w], 1);
    } else {
        for (int e = e0; e < nE; ++e) atomicAdd(&cnt[dst[e]], 1);
    }
}

__global__ __launch_bounds__(256) void scan_blocks(const int* __restrict__ cnt,
                                                   int* __restrict__ rowptr,
                                                   int* __restrict__ partials, int nN) {
    __shared__ int wsum[4];
    const int t = threadIdx.x;
    const int lane = t & 63, wid = t >> 6;
    const int base = blockIdx.x * 1024 + t * 4;

    int4 v = make_int4(0, 0, 0, 0);
    if (base + 3 < nN) {
        v = *reinterpret_cast<const int4*>(cnt + base);
    } else {
        if (base + 0 < nN) v.x = cnt[base + 0];
        if (base + 1 < nN) v.y = cnt[base + 1];
        if (base + 2 < nN) v.z = cnt[base + 2];
        if (base + 3 < nN) v.w = cnt[base + 3];
    }
    const int s = v.x + v.y + v.z + v.w;

    int inc = s;
#pragma unroll
    for (int d = 1; d < 64; d <<= 1) {
        int u = __shfl_up(inc, d);
        if (lane >= d) inc += u;
    }
    if (lane == 63) wsum[wid] = inc;
    __syncthreads();
    int woff = 0;
#pragma unroll
    for (int w = 0; w < 4; ++w) woff += (w < wid) ? wsum[w] : 0;

    const int excl = woff + inc - s;
    int4 o;
    o.x = excl;
    o.y = excl + v.x;
    o.z = excl + v.x + v.y;
    o.w = excl + v.x + v.y + v.z;
    if (base + 3 < nN) {
        *reinterpret_cast<int4*>(rowptr + base) = o;
    } else {
        if (base + 0 < nN) rowptr[base + 0] = o.x;
        if (base + 1 < nN) rowptr[base + 1] = o.y;
        if (base + 2 < nN) rowptr[base + 2] = o.z;
        if (base + 3 < nN) rowptr[base + 3] = o.w;
    }
    if (t == 255) partials[blockIdx.x] = woff + inc;
}

__global__ __launch_bounds__(256) void scan_add(int* __restrict__ rowptr,
                                                const int* __restrict__ partials,
                                                int nN, int nE) {
    __shared__ int soff;
    const int t = threadIdx.x;
    if (t < 64) {
        int v = (t < blockIdx.x) ? partials[t] : 0;   // grid <= 64 blocks
#pragma unroll
        for (int d = 32; d >= 1; d >>= 1) v += __shfl_xor(v, d);
        if (t == 0) soff = v;
    }
    __syncthreads();
    const int off = soff;
    const int base = blockIdx.x * 1024 + t * 4;
    if (base + 3 < nN) {
        int4 v = *reinterpret_cast<int4*>(rowptr + base);
        v.x += off; v.y += off; v.z += off; v.w += off;
        *reinterpret_cast<int4*>(rowptr + base) = v;
    } else {
        if (base + 0 < nN) rowptr[base + 0] += off;
        if (base + 1 < nN) rowptr[base + 1] += off;
        if (base + 2 < nN) rowptr[base + 2] += off;
        if (base + 3 < nN) rowptr[base + 3] += off;
    }
    if (blockIdx.x == 0 && t == 0) rowptr[nN] = nE;
}

__global__ __launch_bounds__(256) void fill_kernel(const int* __restrict__ src,
                                                   const int* __restrict__ dst,
                                                   const int* __restrict__ rowptr,
                                                   int* __restrict__ cursor,
                                                   int* __restrict__ csr_src, int nE) {
    int i = blockIdx.x * blockDim.x + threadIdx.x;
    int e0 = i * 4;
    if (e0 + 3 < nE) {
        int4 s4 = *reinterpret_cast<const int4*>(src + e0);
        int4 d4 = *reinterpret_cast<const int4*>(dst + e0);
        int p0 = atomicAdd(&cursor[d4.x], 1); csr_src[rowptr[d4.x] + p0] = s4.x;
        int p1 = atomicAdd(&cursor[d4.y], 1); csr_src[rowptr[d4.y] + p1] = s4.y;
        int p2 = atomicAdd(&cursor[d4.z], 1); csr_src[rowptr[d4.z] + p2] = s4.z;
        int p3 = atomicAdd(&cursor[d4.w], 1); csr_src[rowptr[d4.w] + p3] = s4.w;
    } else {
        for (int e = e0; e < nE; ++e) {
            int d = dst[e];
            int pos = atomicAdd(&cursor[d], 1);
            csr_src[rowptr[d] + pos] = src[e];
        }
    }
}

// standalone gather (layer 3 final): out[i] = addsrc[i] + mean_{j in N(i)} x[j]
template<int D, bool ADD>
__global__ __launch_bounds__(256) void gather_mean_kernel(
    const float* __restrict__ x, const int* __restrict__ rowptr,
    const int* __restrict__ csr_src, const float* __restrict__ addsrc,
    float* __restrict__ outp, int nN)
{
    constexpr int VPE = D / 4;
    constexpr int NPB = 256 / VPE;
    const int tid = threadIdx.x;
    const int node = blockIdx.x * NPB + tid / VPE;
    const int c = tid % VPE;
    if (node >= nN) return;
    const int beg = rowptr[node];
    const int end = rowptr[node + 1];
    const float4* x4 = reinterpret_cast<const float4*>(x);
    float4 acc = make_float4(0.f, 0.f, 0.f, 0.f);
    int e = beg;
    for (; e + 7 < end; e += 8) {
        int s[8];
#pragma unroll
        for (int j = 0; j < 8; ++j) s[j] = csr_src[e + j];
        float4 v[8];
#pragma unroll
        for (int j = 0; j < 8; ++j) v[j] = x4[(size_t)s[j] * VPE + c];
        acc.x += ((v[0].x + v[1].x) + (v[2].x + v[3].x)) + ((v[4].x + v[5].x) + (v[6].x + v[7].x));
        acc.y += ((v[0].y + v[1].y) + (v[2].y + v[3].y)) + ((v[4].y + v[5].y) + (v[6].y + v[7].y));
        acc.z += ((v[0].z + v[1].z) + (v[2].z + v[3].z)) + ((v[4].z + v[5].z) + (v[6].z + v[7].z));
        acc.w += ((v[0].w + v[1].w) + (v[2].w + v[3].w)) + ((v[4].w + v[5].w) + (v[6].w + v[7].w));
    }
    for (; e + 1 < end; e += 2) {
        int s0 = csr_src[e], s1 = csr_src[e + 1];
        float4 v0 = x4[(size_t)s0 * VPE + c];
        float4 v1 = x4[(size_t)s1 * VPE + c];
        acc.x += v0.x + v1.x; acc.y += v0.y + v1.y;
        acc.z += v0.z + v1.z; acc.w += v0.w + v1.w;
    }
    if (e < end) {
        int s0 = csr_src[e];
        float4 v0 = x4[(size_t)s0 * VPE + c];
        acc.x += v0.x; acc.y += v0.y; acc.z += v0.z; acc.w += v0.w;
    }
    const float sc = 1.0f / (float)max(end - beg, 1);
    float4 o = make_float4(acc.x * sc, acc.y * sc, acc.z * sc, acc.w * sc);
    if constexpr (ADD) {
        float4 a = reinterpret_cast<const float4*>(addsrc)[(size_t)node * VPE + c];
        o.x += a.x; o.y += a.y; o.z += a.z; o.w += a.w;
    }
    reinterpret_cast<float4*>(outp)[(size_t)node * VPE + c] = o;
}

// ---------------------------------------------------------------------------
// One-shot weight prep: hi/lo bf16 fragments in MFMA-ready layout.
// frag f = ((ct*KC+kc)*2+s)*64+lane holds 8 bf16 at k=kc*32+(lane>>4)*8+j,
// col = oc0+ct*16+(lane&15). Sections: [0,1024) L1 K=64 [w1l;w1r];
// [1024,3072) L2 cols 0-63; [3072,5120) L2 cols 64-127; [5120,7168) w3l;
// [7168,9216) w3r.
// ---------------------------------------------------------------------------
__global__ __launch_bounds__(256) void prep_weights(
    const float* __restrict__ w1l, const float* __restrict__ w1r,
    const float* __restrict__ w2l, const float* __restrict__ w2r,
    const float* __restrict__ w3l, const float* __restrict__ w3r,
    ushort* __restrict__ outw)
{
    const int f = blockIdx.x * 256 + threadIdx.x;   // 0..9215
    int base, KCs, oc0, d0, wstride;
    const float *wa, *wb;
    if (f < 1024)      { base = 0;    KCs = 2; oc0 = 0;  wa = w1l; wb = w1r; d0 = 32;  wstride = 64;  }
    else if (f < 3072) { base = 1024; KCs = 4; oc0 = 0;  wa = w2l; wb = w2r; d0 = 64;  wstride = 128; }
    else if (f < 5120) { base = 3072; KCs = 4; oc0 = 64; wa = w2l; wb = w2r; d0 = 64;  wstride = 128; }
    else if (f < 7168) { base = 5120; KCs = 4; oc0 = 0;  wa = w3l; wb = w3l; d0 = 128; wstride = 64;  }
    else               { base = 7168; KCs = 4; oc0 = 0;  wa = w3r; wb = w3r; d0 = 128; wstride = 64;  }
    const int local = f - base;
    const int lane = local & 63;
    const int s = (local >> 6) & 1;
    const int kcct = local >> 7;
    const int kc = kcct % KCs;
    const int ct = kcct / KCs;
    const int col = oc0 + ct * 16 + (lane & 15);
    const int k0 = kc * 32 + (lane >> 4) * 8;
    ushort h8[8];
#pragma unroll
    for (int j = 0; j < 8; ++j) {
        const int k = k0 + j;
        const float* wr = (k < d0) ? (wa + (size_t)k * wstride)
                                   : (wb + (size_t)(k - d0) * wstride);
        const float v = wr[col];
        const ushort h = bf16rn(v);
        h8[j] = (s == 0) ? h : bf16rn(v - bf16tof(h));
    }
    *reinterpret_cast<int4*>(outw + (size_t)f * 8) = *reinterpret_cast<const int4*>(h8);
}

// ---------------------------------------------------------------------------
// Fused gather + split-bf16 MFMA GEMM (layers 1-2):
//   out = relu( [mean_{j in N(i)} xin[j] | xin[i]] @ [wl;wr] + b )
// Block = 64 rows x DOUT cols. Phase G: gather block's 64 neighborhoods into
// LDS f32 tile [64][D0+4] (pad -> <=2-way banks). Phase M: A k<D0 from tile,
// k>=D0 from xin row; split hi/lo; 3 MFMA per 32-k chunk. B fragments:
// WLDS ? staged to LDS : read from L1-hot wprep (all waves share).
// ---------------------------------------------------------------------------
template<int D0, bool WLDS>
__global__ __launch_bounds__(256) void fused_layer(
    const float* __restrict__ xin, const int* __restrict__ rowptr,
    const int* __restrict__ csr_src, const ushort* __restrict__ wfrag,
    const float* __restrict__ bias, float* __restrict__ outp, int nN)
{
    constexpr int K = 2 * D0;           // concat width
    constexpr int DOUT = 2 * D0;        // 64 (L1) / 128 (L2)
    constexpr int KC = K / 32;          // 2 / 4
    constexpr int NCT = DOUT / 16;      // 4 / 8 col tiles
    constexpr int TS = D0 + 4;          // tile stride (floats)
    constexpr int VPE = D0 / 4;         // float4 per row
    constexpr int NPP = 256 / VPE;      // nodes gathered per pass
    constexpr int NFRAG_L1 = 4 * 2 * 2 * 64;   // L1 fragment count

    __shared__ float tile[64 * TS];
    __shared__ ushort wlds[WLDS ? NFRAG_L1 * 8 : 8];

    const int tid = threadIdx.x;
    const int node0 = blockIdx.x * 64;

    if constexpr (WLDS) {   // stage L1 weights (1024 frags, flat copy)
        const int4* wsrc = reinterpret_cast<const int4*>(wfrag);
        int4* wl = reinterpret_cast<int4*>(wlds);
        for (int idx = tid; idx < NFRAG_L1; idx += 256) wl[idx] = wsrc[idx];
    }

    // ---- Phase G: gather mean into tile
    {
        const float4* x4 = reinterpret_cast<const float4*>(xin);
        const int c = tid % VPE;
#pragma unroll
        for (int p = 0; p < 64 / NPP; ++p) {
            const int nl = p * NPP + tid / VPE;
            const int node = node0 + nl;
            float4 acc = make_float4(0.f, 0.f, 0.f, 0.f);
            if (node < nN) {
                const int beg = rowptr[node];
                const int end = rowptr[node + 1];
                int e = beg;
                for (; e + 7 < end; e += 8) {
                    int s[8];
#pragma unroll
                    for (int j = 0; j < 8; ++j) s[j] = csr_src[e + j];
                    float4 v[8];
#pragma unroll
                    for (int j = 0; j < 8; ++j) v[j] = x4[(size_t)s[j] * VPE + c];
                    acc.x += ((v[0].x + v[1].x) + (v[2].x + v[3].x)) + ((v[4].x + v[5].x) + (v[6].x + v[7].x));
                    acc.y += ((v[0].y + v[1].y) + (v[2].y + v[3].y)) + ((v[4].y + v[5].y) + (v[6].y + v[7].y));
                    acc.z += ((v[0].z + v[1].z) + (v[2].z + v[3].z)) + ((v[4].z + v[5].z) + (v[6].z + v[7].z));
                    acc.w += ((v[0].w + v[1].w) + (v[2].w + v[3].w)) + ((v[4].w + v[5].w) + (v[6].w + v[7].w));
                }
                for (; e + 1 < end; e += 2) {
                    int s0 = csr_src[e], s1 = csr_src[e + 1];
                    float4 v0 = x4[(size_t)s0 * VPE + c];
                    float4 v1 = x4[(size_t)s1 * VPE + c];
                    acc.x += v0.x + v1.x; acc.y += v0.y + v1.y;
                    acc.z += v0.z + v1.z; acc.w += v0.w + v1.w;
                }
                if (e < end) {
                    int s0 = csr_src[e];
                    float4 v0 = x4[(size_t)s0 * VPE + c];
                    acc.x += v0.x; acc.y += v0.y; acc.z += v0.z; acc.w += v0.w;
                }
                const float sc = 1.0f / (float)max(end - beg, 1);
                acc.x *= sc; acc.y *= sc; acc.z *= sc; acc.w *= sc;
            }
            *reinterpret_cast<float4*>(&tile[nl * TS + c * 4]) = acc;
        }
    }
    __syncthreads();

    // ---- Phase M
    const int w = tid >> 6;
    const int lane = tid & 63;
    const int row0 = node0 + w * 16;
    const int rloc = (w * 16 + (lane & 15));
    const int arow = min(node0 + (rloc - node0 + node0) - node0 + row0 - row0 + row0 + (lane & 15) - (lane & 15) + (lane & 15), nN - 1); // placeholder avoided below
    const int arow2 = min(row0 + (lane & 15), nN - 1);
    const int kg = lane >> 4;

    bf8 ahi[KC], alo[KC];
#pragma unroll
    for (int kc = 0; kc < KC; ++kc) {
        const int k0 = kc * 32 + kg * 8;
        float v[8];
        if (k0 < D0) {
            const float* tp = &tile[rloc * TS + k0];
            const float4 p = *reinterpret_cast<const float4*>(tp);
            const float4 q = *reinterpret_cast<const float4*>(tp + 4);
            v[0] = p.x; v[1] = p.y; v[2] = p.z; v[3] = p.w;
            v[4] = q.x; v[5] = q.y; v[6] = q.z; v[7] = q.w;
        } else {
            const float* rp = xin + (size_t)arow2 * D0 + (k0 - D0);
            const float4 p = *reinterpret_cast<const float4*>(rp);
            const float4 q = *reinterpret_cast<const float4*>(rp + 4);
            v[0] = p.x; v[1] = p.y; v[2] = p.z; v[3] = p.w;
            v[4] = q.x; v[5] = q.y; v[6] = q.z; v[7] = q.w;
        }
        bf8 A, L;
#pragma unroll
        for (int j = 0; j < 8; ++j) {
            const ushort h = bf16rn(v[j]);
            A[j] = (short)h;
            L[j] = (short)bf16rn(v[j] - bf16tof(h));
        }
        ahi[kc] = A;
        alo[kc] = L;
    }

#pragma unroll
    for (int ct = 0; ct < NCT; ++ct) {
        f32x4 acc = {0.f, 0.f, 0.f, 0.f};
#pragma unroll
        for (int kc = 0; kc < KC; ++kc) {
            bf8 bhi, blo;
            if constexpr (WLDS) {
                const bf8* bl = reinterpret_cast<const bf8*>(wlds);
                bhi = bl[((ct * KC + kc) * 2 + 0) * 64 + lane];
                blo = bl[((ct * KC + kc) * 2 + 1) * 64 + lane];
            } else {
                // sections of 2048 frags per 64-col half (L2 layout)
                const int sec = ct >> 2;
                const int ctl = ct & 3;
                const bf8* bg = reinterpret_cast<const bf8*>(wfrag) + sec * 2048;
                bhi = bg[((ctl * KC + kc) * 2 + 0) * 64 + lane];
                blo = bg[((ctl * KC + kc) * 2 + 1) * 64 + lane];
            }
            acc = __builtin_amdgcn_mfma_f32_16x16x32_bf16(ahi[kc], bhi, acc, 0, 0, 0);
            acc = __builtin_amdgcn_mfma_f32_16x16x32_bf16(ahi[kc], blo, acc, 0, 0, 0);
            acc = __builtin_amdgcn_mfma_f32_16x16x32_bf16(alo[kc], bhi, acc, 0, 0, 0);
        }
        const int col = ct * 16 + (lane & 15);
        const float bv = bias[col];
#pragma unroll
        for (int r = 0; r < 4; ++r) {
            const int node = row0 + (lane >> 4) * 4 + r;
            if (node < nN) {
                float o = fmaxf(acc[r] + bv, 0.f);
                outp[(size_t)node * DOUT + col] = o;
            }
        }
    }
}

// ---------------------------------------------------------------------------
// Pure GEMM (layer 3 DUAL): weights LDS-staged. Same math as R6.
// ---------------------------------------------------------------------------
template<int K, bool BIAS>
__global__ __launch_bounds__(256) void mfma_xform_dual(
    const float* __restrict__ r0, const ushort* __restrict__ wfrag,
    const float* __restrict__ bias, float* __restrict__ out0,
    float* __restrict__ out1, int ostride, int nN)
{
    constexpr int KC = K / 32;
    constexpr int NFRAG = 4 * KC * 2 * 64;
    __shared__ ushort wlds[NFRAG * 8];

    const int tid = threadIdx.x;
    const int sel = blockIdx.y;
    float* __restrict__ outp = sel ? out1 : out0;

    {
        const int4* wsrc = reinterpret_cast<const int4*>(wfrag) + (size_t)sel * NFRAG;
        int4* wl = reinterpret_cast<int4*>(wlds);
        for (int idx = tid; idx < NFRAG; idx += 256) wl[idx] = wsrc[idx];
    }
    __syncthreads();

    const int w = tid >> 6;
    const int lane = tid & 63;
    const int row0 = blockIdx.x * 64 + w * 16;
    const int arow = min(row0 + (lane & 15), nN - 1);
    const int kg = lane >> 4;

    bf8 ahi[KC], alo[KC];
#pragma unroll
    for (int kc = 0; kc < KC; ++kc) {
        const int k0 = kc * 32 + kg * 8;
        const float* rp = r0 + (size_t)arow * K + k0;
        const float4 p = *reinterpret_cast<const float4*>(rp);
        const float4 q = *reinterpret_cast<const float4*>(rp + 4);
        const float v[8] = {p.x, p.y, p.z, p.w, q.x, q.y, q.z, q.w};
        bf8 A, L;
#pragma unroll
        for (int j = 0; j < 8; ++j) {
            const ushort h = bf16rn(v[j]);
            A[j] = (short)h;
            L[j] = (short)bf16rn(v[j] - bf16tof(h));
        }
        ahi[kc] = A;
        alo[kc] = L;
    }

    const bf8* bl = reinterpret_cast<const bf8*>(wlds);
#pragma unroll
    for (int ct = 0; ct < 4; ++ct) {
        f32x4 acc = {0.f, 0.f, 0.f, 0.f};
#pragma unroll
        for (int kc = 0; kc < KC; ++kc) {
            const bf8 bhi = bl[((ct * KC + kc) * 2 + 0) * 64 + lane];
            const bf8 blo = bl[((ct * KC + kc) * 2 + 1) * 64 + lane];
            acc = __builtin_amdgcn_mfma_f32_16x16x32_bf16(ahi[kc], bhi, acc, 0, 0, 0);
            acc = __builtin_amdgcn_mfma_f32_16x16x32_bf16(ahi[kc], blo, acc, 0, 0, 0);
            acc = __builtin_amdgcn_mfma_f32_16x16x32_bf16(alo[kc], bhi, acc, 0, 0, 0);
        }
        const int col = ct * 16 + (lane & 15);
        float bv = 0.f;
        if (BIAS && sel) bv = bias[col];
#pragma unroll
        for (int r = 0; r < 4; ++r) {
            const int node = row0 + (lane >> 4) * 4 + r;
            if (node < nN) {
                outp[(size_t)node * ostride + col] = acc[r] + bv;
            }
        }
    }
}

extern "C" void kernel_launch(void* const* d_in, const int* in_sizes, int n_in,
                              void* d_out, int out_size, void* d_ws, size_t ws_size,
                              hipStream_t stream) {
    const float* x   = (const float*)d_in[0];
    const int*   ei  = (const int*)d_in[1];
    const float* w1l = (const float*)d_in[2];
    const float* b1  = (const float*)d_in[3];
    const float* w1r = (const float*)d_in[4];
    const float* w2l = (const float*)d_in[5];
    const float* b2  = (const float*)d_in[6];
    const float* w2r = (const float*)d_in[7];
    const float* w3l = (const float*)d_in[8];
    const float* b3  = (const float*)d_in[9];
    const float* w3r = (const float*)d_in[10];

    const int nN = in_sizes[0] / 32;   // 50000
    const int nE = in_sizes[1] / 2;    // 640000
    const int* src = ei;
    const int* dst = ei + nE;
    const int nB = (nN + 1023) / 1024; // 49 scan blocks (<= 64)

    char* ws = (char*)d_ws;
    size_t o = 0;
    auto alloc = [&](size_t nbytes) {
        char* p = ws + o;
        o += (nbytes + 255) & ~(size_t)255;
        return p;
    };
    int*    cnt      = (int*)alloc(((size_t)nN * 2 + 64) * sizeof(int)); // cnt + cursor
    int*    cursor   = cnt + nN + 32;
    int*    partials = (int*)alloc(64 * sizeof(int));
    int*    rowptr   = (int*)alloc(((size_t)nN + 1) * sizeof(int));
    int*    csr_src  = (int*)alloc((size_t)nE * sizeof(int));
    ushort* wprep    = (ushort*)alloc((size_t)9216 * 8 * sizeof(ushort)); // 144KB
    float*  h1       = (float*)alloc((size_t)nN * 64 * sizeof(float));
    float*  h2       = (float*)alloc((size_t)nN * 128 * sizeof(float));
    float*  r3       = (float*)alloc((size_t)nN * 64 * sizeof(float));
    float*  t3       = h1;    // h1 dead after fused layer 2

    const int nzero4 = (int)(((size_t)nN * 2 + 64) / 4);

    // ---- weight prep (independent of edges)
    prep_weights<<<36, 256, 0, stream>>>(w1l, w1r, w2l, w2r, w3l, w3r, wprep);

    // ---- CSR build
    zero_kernel<<<(nzero4 + 255) / 256, 256, 0, stream>>>((int4*)cnt, nzero4);
    count_kernel<<<(nE / 4 + 255) / 256, 256, 0, stream>>>(dst, cnt, nE);
    scan_blocks<<<nB, 256, 0, stream>>>(cnt, rowptr, partials, nN);
    scan_add<<<nB, 256, 0, stream>>>(rowptr, partials, nN, nE);
    fill_kernel<<<(nE / 4 + 255) / 256, 256, 0, stream>>>(src, dst, rowptr, cursor, csr_src, nE);

    const int xblk = (nN + 63) / 64;   // 782 blocks of 64 rows

    // ---- layer 1 (fused): h1 = relu([mean(x)|x] @ [w1l;w1r] + b1)
    fused_layer<32, true><<<xblk, 256, 0, stream>>>(
        x, rowptr, csr_src, wprep, b1, h1, nN);

    // ---- layer 2 (fused): h2 = relu([mean(h1)|h1] @ [w2l;w2r] + b2)
    fused_layer<64, false><<<xblk, 256, 0, stream>>>(
        h1, rowptr, csr_src, wprep + (size_t)1024 * 8, b2, h2, nN);

    // ---- layer 3: t3 = h2@w3l; r3 = h2@w3r + b3; out = r3 + mean(t3)
    mfma_xform_dual<128, true><<<dim3(xblk, 2), 256, 0, stream>>>(
        h2, wprep + (size_t)5120 * 8, b3, t3, r3, 64, nN);
    gather_mean_kernel<64, true><<<(nN + 15) / 16, 256, 0, stream>>>(
        t3, rowptr, csr_src, r3, (float*)d_out, nN);
}